// Round 1
// baseline (3274.092 us; speedup 1.0000x reference)
//
#include <hip/hip_runtime.h>

#define N_NODES 100000
#define N_EDGES 1600000
#define HIDDEN 64
#define OUT_CH 16
#define N_GRAPHS 64

// ---------------------------------------------------------------------------
// Layer 1 edge propagation: x is [N,1]; agg1[d] += w_e * x[src_e]
__global__ __launch_bounds__(256) void k_edge1(
    const int* __restrict__ src, const int* __restrict__ dst,
    const float* __restrict__ w, const float* __restrict__ x,
    float* __restrict__ agg1)
{
    int e = blockIdx.x * 256 + threadIdx.x;
    if (e < N_EDGES) {
        atomicAdd(&agg1[dst[e]], w[e] * x[src[e]]);
    }
}

// h1[i][c] = relu(agg1[i]*Wr[c] + b[c] + x[i]*Wo[c])   (W_rel1/W_root1 are [64,1])
__global__ __launch_bounds__(256) void k_h1(
    const float* __restrict__ x, const float* __restrict__ agg1,
    const float* __restrict__ Wr, const float* __restrict__ b,
    const float* __restrict__ Wo, float* __restrict__ h1)
{
    int tid = blockIdx.x * 256 + threadIdx.x;
    int i = tid >> 6, c = tid & 63;
    if (i < N_NODES) {
        float v = fmaf(agg1[i], Wr[c], fmaf(x[i], Wo[c], b[c]));
        h1[tid] = fmaxf(v, 0.0f);
    }
}

// 64-channel edge propagation: 16 lanes per edge, float4 per lane.
// Gather = one contiguous 256B segment per edge; atomics = 4 consecutive
// floats per lane (contiguous 256B per edge across 16 lanes).
__global__ __launch_bounds__(256) void k_edge_prop(
    const int* __restrict__ src, const int* __restrict__ dst,
    const float* __restrict__ w, const float* __restrict__ h,
    float* __restrict__ agg)
{
    int tid = blockIdx.x * 256 + threadIdx.x;
    int e = tid >> 4, sub = tid & 15;
    if (e < N_EDGES) {
        int s = src[e], d = dst[e];
        float we = w[e];
        float4 v = ((const float4*)h)[s * 16 + sub];
        float* out = agg + d * 64 + sub * 4;
        atomicAdd(out + 0, we * v.x);
        atomicAdd(out + 1, we * v.y);
        atomicAdd(out + 2, we * v.z);
        atomicAdd(out + 3, we * v.w);
    }
}

// h_out[i][c] = act( sum_k agg[i][k]*Wrel[c][k] + brel[c] + sum_k h_in[i][k]*Wroot[c][k] )
// One wave per node (lanes = 64 channels). Weights staged transposed in LDS
// (padded stride 65 -> conflict-free broadcast reads). Row data via per-wave
// same-address float4 loads (single transaction, L1-resident).
template<int RELU>
__global__ __launch_bounds__(256) void k_transform(
    const float* __restrict__ agg, const float* __restrict__ h_in,
    const float* __restrict__ Wrel, const float* __restrict__ brel,
    const float* __restrict__ Wroot, float* __restrict__ h_out)
{
    __shared__ float sR[64][65];   // sR[k][c] = Wrel[c][k]
    __shared__ float sO[64][65];
    int t = threadIdx.x;
    for (int i = t; i < 4096; i += 256) {
        int c = i >> 6, k = i & 63;
        sR[k][c] = Wrel[i];
        sO[k][c] = Wroot[i];
    }
    __syncthreads();
    int node = blockIdx.x * 4 + (t >> 6);
    int c = t & 63;
    if (node >= N_NODES) return;
    const float4* av = (const float4*)(agg + node * 64);
    const float4* hv = (const float4*)(h_in + node * 64);
    float acc = brel[c];
    #pragma unroll
    for (int k4 = 0; k4 < 16; ++k4) {
        float4 a = av[k4];
        float4 h = hv[k4];
        acc = fmaf(a.x, sR[4 * k4 + 0][c], acc);
        acc = fmaf(a.y, sR[4 * k4 + 1][c], acc);
        acc = fmaf(a.z, sR[4 * k4 + 2][c], acc);
        acc = fmaf(a.w, sR[4 * k4 + 3][c], acc);
        acc = fmaf(h.x, sO[4 * k4 + 0][c], acc);
        acc = fmaf(h.y, sO[4 * k4 + 1][c], acc);
        acc = fmaf(h.z, sO[4 * k4 + 2][c], acc);
        acc = fmaf(h.w, sO[4 * k4 + 3][c], acc);
    }
    if (RELU) acc = fmaxf(acc, 0.0f);
    h_out[node * 64 + c] = acc;
}

// Mean-pool per graph (batch is sorted -> binary-search boundaries) fused with
// the final 64->16 linear layer. One block per graph.
__global__ __launch_bounds__(256) void k_pool(
    const float* __restrict__ h, const int* __restrict__ batch,
    const float* __restrict__ Wlin, const float* __restrict__ blin,
    float* __restrict__ out)
{
    int g = blockIdx.x;
    int t = threadIdx.x;
    int c = t & 63, seg = t >> 6;

    // lower_bound(batch, g) / lower_bound(batch, g+1)
    int lo = 0, hi = N_NODES;
    while (lo < hi) { int mid = (lo + hi) >> 1; if (batch[mid] < g) lo = mid + 1; else hi = mid; }
    int s0 = lo;
    lo = 0; hi = N_NODES;
    while (lo < hi) { int mid = (lo + hi) >> 1; if (batch[mid] < g + 1) lo = mid + 1; else hi = mid; }
    int s1 = lo;

    __shared__ float sums[256];
    float acc = 0.0f;
    for (int i = s0 + seg; i < s1; i += 4) acc += h[i * 64 + c];
    sums[t] = acc;
    __syncthreads();
    if (t < 64) {
        float v = sums[t] + sums[t + 64] + sums[t + 128] + sums[t + 192];
        float cnt = (float)(s1 - s0);
        sums[t] = v / fmaxf(cnt, 1.0f);
    }
    __syncthreads();
    if (t < OUT_CH) {
        float acc2 = blin[t];
        #pragma unroll 8
        for (int k = 0; k < HIDDEN; ++k) acc2 += sums[k] * Wlin[t * 64 + k];
        out[g * OUT_CH + t] = acc2;
    }
}

// ---------------------------------------------------------------------------
extern "C" void kernel_launch(void* const* d_in, const int* in_sizes, int n_in,
                              void* d_out, int out_size, void* d_ws, size_t ws_size,
                              hipStream_t stream)
{
    const float* x    = (const float*)d_in[0];
    const int*   ei   = (const int*)d_in[1];      // [2, E]: row0=src, row1=dst
    const int*   src  = ei;
    const int*   dst  = ei + N_EDGES;
    const float* ew   = (const float*)d_in[2];
    const int*   batch= (const int*)d_in[3];
    const float* Wr1  = (const float*)d_in[4];
    const float* b1   = (const float*)d_in[5];
    const float* Wo1  = (const float*)d_in[6];
    const float* Wr2  = (const float*)d_in[7];
    const float* b2   = (const float*)d_in[8];
    const float* Wo2  = (const float*)d_in[9];
    const float* Wr3  = (const float*)d_in[10];
    const float* b3   = (const float*)d_in[11];
    const float* Wo3  = (const float*)d_in[12];
    const float* Wlin = (const float*)d_in[13];
    const float* blin = (const float*)d_in[14];
    float* out = (float*)d_out;

    // workspace layout (all 256B-aligned):
    //   agg1: N f32 (0.4MB) | h1: N*64 f32 (25.6MB) | agg: 25.6MB | h2: 25.6MB
    char* ws = (char*)d_ws;
    const size_t MB = 1024 * 1024;
    float* agg1 = (float*)ws;
    float* h1   = (float*)(ws + 1 * MB);
    float* agg  = (float*)(ws + 27 * MB);
    float* h2   = (float*)(ws + 53 * MB);

    hipMemsetAsync(agg1, 0, N_NODES * sizeof(float), stream);
    k_edge1<<<(N_EDGES + 255) / 256, 256, 0, stream>>>(src, dst, ew, x, agg1);
    k_h1<<<(N_NODES * 64) / 256, 256, 0, stream>>>(x, agg1, Wr1, b1, Wo1, h1);

    hipMemsetAsync(agg, 0, (size_t)N_NODES * 64 * sizeof(float), stream);
    k_edge_prop<<<(N_EDGES * 16) / 256, 256, 0, stream>>>(src, dst, ew, h1, agg);
    k_transform<1><<<N_NODES / 4, 256, 0, stream>>>(agg, h1, Wr2, b2, Wo2, h2);

    hipMemsetAsync(agg, 0, (size_t)N_NODES * 64 * sizeof(float), stream);
    k_edge_prop<<<(N_EDGES * 16) / 256, 256, 0, stream>>>(src, dst, ew, h2, agg);
    k_transform<0><<<N_NODES / 4, 256, 0, stream>>>(agg, h2, Wr3, b3, Wo3, h1); // h3 -> h1 buf

    k_pool<<<N_GRAPHS, 256, 0, stream>>>(h1, batch, Wlin, blin, out);
}

// Round 2
// 850.750 us; speedup vs baseline: 3.8485x; 3.8485x over previous
//
#include <hip/hip_runtime.h>

#define N_NODES 100000
#define N_EDGES 1600000
#define HIDDEN 64
#define OUT_CH 16
#define N_GRAPHS 64
#define SCAN_B 256
#define NB1 ((N_NODES + SCAN_B - 1) / SCAN_B)   // 391 scan blocks

__device__ __forceinline__ float lane_bcast(float v, int l) {
    return __uint_as_float(__builtin_amdgcn_readlane(__float_as_uint(v), l));
}

// ---------------------------------------------------------------------------
// CSR build step 1: histogram of dst
__global__ __launch_bounds__(256) void k_hist(const int* __restrict__ dst, int* __restrict__ cnt) {
    int e = blockIdx.x * 256 + threadIdx.x;
    if (e < N_EDGES) atomicAdd(&cnt[dst[e]], 1);
}

// step 2a: per-block sums of cnt
__global__ __launch_bounds__(SCAN_B) void k_partial(const int* __restrict__ cnt, int* __restrict__ bsum) {
    __shared__ int s[SCAN_B];
    int b = blockIdx.x, t = threadIdx.x;
    int i = b * SCAN_B + t;
    s[t] = (i < N_NODES) ? cnt[i] : 0;
    __syncthreads();
    for (int off = SCAN_B / 2; off > 0; off >>= 1) {
        if (t < off) s[t] += s[t + off];
        __syncthreads();
    }
    if (t == 0) bsum[b] = s[0];
}

// step 2b: exclusive scan of the 391 block sums (single block)
__global__ __launch_bounds__(512) void k_scan_bsum(const int* __restrict__ bsum, int* __restrict__ boff) {
    __shared__ int s[512];
    int t = threadIdx.x;
    int v = (t < NB1) ? bsum[t] : 0;
    s[t] = v;
    __syncthreads();
    for (int off = 1; off < 512; off <<= 1) {
        int x = (t >= off) ? s[t - off] : 0;
        __syncthreads();
        s[t] += x;
        __syncthreads();
    }
    if (t < NB1) boff[t] = s[t] - v;   // exclusive
}

// step 2c: per-block exclusive scan + block offset -> row_ptr; init cursor
__global__ __launch_bounds__(SCAN_B) void k_scan_final(const int* __restrict__ cnt, const int* __restrict__ boff,
                                                       int* __restrict__ row_ptr, int* __restrict__ cursor) {
    __shared__ int s[SCAN_B];
    int b = blockIdx.x, t = threadIdx.x;
    int i = b * SCAN_B + t;
    int v = (i < N_NODES) ? cnt[i] : 0;
    s[t] = v;
    __syncthreads();
    for (int off = 1; off < SCAN_B; off <<= 1) {
        int x = (t >= off) ? s[t - off] : 0;
        __syncthreads();
        s[t] += x;
        __syncthreads();
    }
    if (i < N_NODES) {
        int rp = boff[b] + s[t] - v;
        row_ptr[i] = rp;
        cursor[i] = rp;
    }
    if (b == 0 && t == 0) row_ptr[N_NODES] = N_EDGES;
}

// step 3: scatter edges into CSR order (bucketed by dst)
__global__ __launch_bounds__(256) void k_scatter(const int* __restrict__ src, const int* __restrict__ dst,
                                                 const float* __restrict__ w, int* __restrict__ cursor,
                                                 int* __restrict__ src_csr, float* __restrict__ w_csr) {
    int e = blockIdx.x * 256 + threadIdx.x;
    if (e < N_EDGES) {
        int pos = atomicAdd(&cursor[dst[e]], 1);
        src_csr[pos] = src[e];
        w_csr[pos] = w[e];
    }
}

// ---------------------------------------------------------------------------
// Layer 1 aggregation (C=1): thread per node, CSR loop, no atomics
__global__ __launch_bounds__(256) void k_agg1(const int* __restrict__ rp, const int* __restrict__ src_csr,
                                              const float* __restrict__ w_csr, const float* __restrict__ x,
                                              float* __restrict__ agg1) {
    int i = blockIdx.x * 256 + threadIdx.x;
    if (i >= N_NODES) return;
    int j1 = rp[i + 1];
    float acc = 0.0f;
    for (int j = rp[i]; j < j1; ++j)
        acc = fmaf(w_csr[j], x[src_csr[j]], acc);
    agg1[i] = acc;
}

// h1[i][c] = relu(agg1[i]*Wr[c] + b[c] + x[i]*Wo[c])   (W_rel1/W_root1 are [64,1])
__global__ __launch_bounds__(256) void k_h1(
    const float* __restrict__ x, const float* __restrict__ agg1,
    const float* __restrict__ Wr, const float* __restrict__ b,
    const float* __restrict__ Wo, float* __restrict__ h1)
{
    int tid = blockIdx.x * 256 + threadIdx.x;
    int i = tid >> 6, c = tid & 63;
    if (i < N_NODES) {
        float v = fmaf(agg1[i], Wr[c], fmaf(x[i], Wo[c], b[c]));
        h1[tid] = fmaxf(v, 0.0f);
    }
}

// ---------------------------------------------------------------------------
// 64-channel aggregation: one wave per node, lane = channel. Each edge is one
// coalesced 256B row gather; accumulate in registers; one coalesced row store.
__global__ __launch_bounds__(256) void k_gather(const int* __restrict__ rp, const int* __restrict__ src_csr,
                                                const float* __restrict__ w_csr, const float* __restrict__ h,
                                                float* __restrict__ agg) {
    int t = blockIdx.x * 256 + threadIdx.x;
    int node = t >> 6, c = t & 63;
    if (node >= N_NODES) return;
    int j0 = rp[node], j1 = rp[node + 1];
    float acc = 0.0f;
    for (int j = j0; j < j1; ++j) {
        int s = src_csr[j];          // wave-uniform -> broadcast
        float ww = w_csr[j];
        acc = fmaf(ww, h[s * 64 + c], acc);
    }
    agg[node * 64 + c] = acc;
}

// ---------------------------------------------------------------------------
// In-place transform: agg[i] := act(agg[i] @ Wrel^T + b + h_root[i] @ Wroot^T).
// One wave per node (grid-stride). Lane c holds weight ROWS c of both matrices
// in 128 VGPRs; the 64 cross-lane values come from v_readlane (no LDS).
template<int RELU>
__global__ __launch_bounds__(256) void k_transform(
    float* __restrict__ agg, const float* __restrict__ h_root,
    const float* __restrict__ Wrel, const float* __restrict__ brel,
    const float* __restrict__ Wroot)
{
    int t = threadIdx.x;
    int wv = t >> 6, c = t & 63;
    float rR[64], rO[64];
    #pragma unroll
    for (int q = 0; q < 16; ++q) {
        float4 a = ((const float4*)(Wrel + c * 64))[q];
        rR[4 * q + 0] = a.x; rR[4 * q + 1] = a.y; rR[4 * q + 2] = a.z; rR[4 * q + 3] = a.w;
        float4 b = ((const float4*)(Wroot + c * 64))[q];
        rO[4 * q + 0] = b.x; rO[4 * q + 1] = b.y; rO[4 * q + 2] = b.z; rO[4 * q + 3] = b.w;
    }
    float bc = brel[c];
    int gw = blockIdx.x * 4 + wv;
    int nw = gridDim.x * 4;
    for (int i = gw; i < N_NODES; i += nw) {
        float av = agg[i * 64 + c];
        float hv = h_root[i * 64 + c];
        float acc = bc;
        #pragma unroll
        for (int k = 0; k < 64; ++k) {
            acc = fmaf(lane_bcast(av, k), rR[k], acc);
            acc = fmaf(lane_bcast(hv, k), rO[k], acc);
        }
        if (RELU) acc = fmaxf(acc, 0.0f);
        agg[i * 64 + c] = acc;
    }
}

// ---------------------------------------------------------------------------
// Mean-pool per graph + final 64->16 linear. One block per graph.
__global__ __launch_bounds__(256) void k_pool(
    const float* __restrict__ h, const int* __restrict__ batch,
    const float* __restrict__ Wlin, const float* __restrict__ blin,
    float* __restrict__ out)
{
    int g = blockIdx.x;
    int t = threadIdx.x;
    int c = t & 63, seg = t >> 6;

    int lo = 0, hi = N_NODES;
    while (lo < hi) { int mid = (lo + hi) >> 1; if (batch[mid] < g) lo = mid + 1; else hi = mid; }
    int s0 = lo;
    lo = 0; hi = N_NODES;
    while (lo < hi) { int mid = (lo + hi) >> 1; if (batch[mid] < g + 1) lo = mid + 1; else hi = mid; }
    int s1 = lo;

    __shared__ float sums[256];
    float acc = 0.0f;
    for (int i = s0 + seg; i < s1; i += 4) acc += h[i * 64 + c];
    sums[t] = acc;
    __syncthreads();
    if (t < 64) {
        float v = sums[t] + sums[t + 64] + sums[t + 128] + sums[t + 192];
        float cnt = (float)(s1 - s0);
        sums[t] = v / fmaxf(cnt, 1.0f);
    }
    __syncthreads();
    if (t < OUT_CH) {
        float acc2 = blin[t];
        #pragma unroll 8
        for (int k = 0; k < HIDDEN; ++k) acc2 += sums[k] * Wlin[t * 64 + k];
        out[g * OUT_CH + t] = acc2;
    }
}

// ---------------------------------------------------------------------------
extern "C" void kernel_launch(void* const* d_in, const int* in_sizes, int n_in,
                              void* d_out, int out_size, void* d_ws, size_t ws_size,
                              hipStream_t stream)
{
    const float* x    = (const float*)d_in[0];
    const int*   ei   = (const int*)d_in[1];      // [2, E]: row0=src, row1=dst
    const int*   src  = ei;
    const int*   dst  = ei + N_EDGES;
    const float* ew   = (const float*)d_in[2];
    const int*   batch= (const int*)d_in[3];
    const float* Wr1  = (const float*)d_in[4];
    const float* b1   = (const float*)d_in[5];
    const float* Wo1  = (const float*)d_in[6];
    const float* Wr2  = (const float*)d_in[7];
    const float* b2   = (const float*)d_in[8];
    const float* Wo2  = (const float*)d_in[9];
    const float* Wr3  = (const float*)d_in[10];
    const float* b3   = (const float*)d_in[11];
    const float* Wo3  = (const float*)d_in[12];
    const float* Wlin = (const float*)d_in[13];
    const float* blin = (const float*)d_in[14];
    float* out = (float*)d_out;

    // workspace layout (top = 66 MB; 78.6 MB was proven safe in round 0)
    char* ws = (char*)d_ws;
    const size_t K = 1024;
    int*   row_ptr = (int*)(ws + 0);            // 100001 ints
    int*   cursor  = (int*)(ws + 512 * K);      // doubles as cnt
    int*   bsum    = (int*)(ws + 1024 * K);
    int*   boff    = (int*)(ws + 1032 * K);
    float* agg1    = (float*)(ws + 1280 * K);
    int*   src_csr = (int*)(ws + 2048 * K);     // 6.4 MB
    float* w_csr   = (float*)(ws + 8704 * K);   // 6.4 MB
    float* bufA    = (float*)(ws + 15360 * K);  // 25.6 MB
    float* bufB    = (float*)(ws + 41984 * K);  // 25.6 MB

    // ---- CSR build (bucket edges by dst) ----
    hipMemsetAsync(cursor, 0, N_NODES * sizeof(int), stream);
    k_hist<<<N_EDGES / 256, 256, 0, stream>>>(dst, cursor);
    k_partial<<<NB1, SCAN_B, 0, stream>>>(cursor, bsum);
    k_scan_bsum<<<1, 512, 0, stream>>>(bsum, boff);
    k_scan_final<<<NB1, SCAN_B, 0, stream>>>(cursor, boff, row_ptr, cursor);
    k_scatter<<<N_EDGES / 256, 256, 0, stream>>>(src, dst, ew, cursor, src_csr, w_csr);

    // ---- layer 1 (C=1) ----
    k_agg1<<<NB1, 256, 0, stream>>>(row_ptr, src_csr, w_csr, x, agg1);
    k_h1<<<(N_NODES * 64) / 256, 256, 0, stream>>>(x, agg1, Wr1, b1, Wo1, bufA); // bufA = h1

    // ---- layer 2 ----
    k_gather<<<(N_NODES * 64) / 256, 256, 0, stream>>>(row_ptr, src_csr, w_csr, bufA, bufB);
    k_transform<1><<<1024, 256, 0, stream>>>(bufB, bufA, Wr2, b2, Wo2);          // bufB = h2

    // ---- layer 3 ----
    k_gather<<<(N_NODES * 64) / 256, 256, 0, stream>>>(row_ptr, src_csr, w_csr, bufB, bufA);
    k_transform<0><<<1024, 256, 0, stream>>>(bufA, bufB, Wr3, b3, Wo3);          // bufA = h3

    // ---- pool + linear ----
    k_pool<<<N_GRAPHS, 256, 0, stream>>>(bufA, batch, Wlin, blin, out);
}

// Round 3
// 668.137 us; speedup vs baseline: 4.9003x; 1.2733x over previous
//
#include <hip/hip_runtime.h>

#define N_NODES 100000
#define N_EDGES 1600000
#define HIDDEN 64
#define OUT_CH 16
#define N_GRAPHS 64
#define SCAN_B 256
#define NB1 ((N_NODES + SCAN_B - 1) / SCAN_B)   // 391 scan blocks

__device__ __forceinline__ float lane_bcast(float v, int l) {
    return __uint_as_float(__builtin_amdgcn_readlane(__float_as_uint(v), l));
}
__device__ __forceinline__ float bfu(unsigned short u) {            // bf16 -> f32
    return __uint_as_float(((unsigned)u) << 16);
}
__device__ __forceinline__ unsigned short f2bf(float x) {           // f32 -> bf16 RTN
    unsigned u = __float_as_uint(x);
    return (unsigned short)((u + 0x7FFFu + ((u >> 16) & 1u)) >> 16);
}

// ---------------------------------------------------------------------------
// CSR build
__global__ __launch_bounds__(256) void k_hist(const int* __restrict__ dst, int* __restrict__ cnt) {
    int e = blockIdx.x * 256 + threadIdx.x;
    if (e < N_EDGES) atomicAdd(&cnt[dst[e]], 1);
}

__global__ __launch_bounds__(SCAN_B) void k_partial(const int* __restrict__ cnt, int* __restrict__ bsum) {
    __shared__ int s[SCAN_B];
    int b = blockIdx.x, t = threadIdx.x;
    int i = b * SCAN_B + t;
    s[t] = (i < N_NODES) ? cnt[i] : 0;
    __syncthreads();
    for (int off = SCAN_B / 2; off > 0; off >>= 1) {
        if (t < off) s[t] += s[t + off];
        __syncthreads();
    }
    if (t == 0) bsum[b] = s[0];
}

__global__ __launch_bounds__(512) void k_scan_bsum(const int* __restrict__ bsum, int* __restrict__ boff) {
    __shared__ int s[512];
    int t = threadIdx.x;
    int v = (t < NB1) ? bsum[t] : 0;
    s[t] = v;
    __syncthreads();
    for (int off = 1; off < 512; off <<= 1) {
        int x = (t >= off) ? s[t - off] : 0;
        __syncthreads();
        s[t] += x;
        __syncthreads();
    }
    if (t < NB1) boff[t] = s[t] - v;   // exclusive
}

__global__ __launch_bounds__(SCAN_B) void k_scan_final(const int* __restrict__ cnt, const int* __restrict__ boff,
                                                       int* __restrict__ row_ptr, int* __restrict__ cursor) {
    __shared__ int s[SCAN_B];
    int b = blockIdx.x, t = threadIdx.x;
    int i = b * SCAN_B + t;
    int v = (i < N_NODES) ? cnt[i] : 0;
    s[t] = v;
    __syncthreads();
    for (int off = 1; off < SCAN_B; off <<= 1) {
        int x = (t >= off) ? s[t - off] : 0;
        __syncthreads();
        s[t] += x;
        __syncthreads();
    }
    if (i < N_NODES) {
        int rp = boff[b] + s[t] - v;
        row_ptr[i] = rp;
        cursor[i] = rp;
    }
    if (b == 0 && t == 0) row_ptr[N_NODES] = N_EDGES;
}

// scatter edges into CSR order; packed (src, w-bits) per edge -> one 8B store
__global__ __launch_bounds__(256) void k_scatter(const int* __restrict__ src, const int* __restrict__ dst,
                                                 const float* __restrict__ w, int* __restrict__ cursor,
                                                 int2* __restrict__ E) {
    int e = blockIdx.x * 256 + threadIdx.x;
    if (e < N_EDGES) {
        int pos = atomicAdd(&cursor[dst[e]], 1);
        E[pos] = make_int2(src[e], __float_as_int(w[e]));
    }
}

// ---------------------------------------------------------------------------
// Layer 1 (C=1) aggregation + pair pack: p[i] = (agg1[i], x[i])
__global__ __launch_bounds__(256) void k_agg1_pair(const int* __restrict__ rp, const int2* __restrict__ E,
                                                   const float* __restrict__ x, float2* __restrict__ p) {
    int i = blockIdx.x * 256 + threadIdx.x;
    if (i >= N_NODES) return;
    int j1 = rp[i + 1];
    float acc = 0.0f;
    for (int j = rp[i]; j < j1; ++j) {
        int2 e = E[j];
        acc = fmaf(__int_as_float(e.y), x[e.x], acc);
    }
    p[i] = make_float2(acc, x[i]);
}

// ---------------------------------------------------------------------------
// Layer-2 aggregation: gather 8B pairs (L2-resident), reconstruct h1[s][c]
// in-lane. One wave per node, lane = channel. 4-deep pipelined.
__global__ __launch_bounds__(256) void k_gather_pair(
    const int* __restrict__ rp, const int2* __restrict__ E,
    const float2* __restrict__ p,
    const float* __restrict__ Wr1, const float* __restrict__ b1,
    const float* __restrict__ Wo1, float* __restrict__ agg)
{
    int t = blockIdx.x * 256 + threadIdx.x;
    int node = t >> 6, c = t & 63;
    if (node >= N_NODES) return;
    float wr = Wr1[c], bb = b1[c], wo = Wo1[c];
    int j0 = rp[node], j1 = rp[node + 1];
    float acc = 0.0f;
    int j = j0;
    int2 e0, e1, e2, e3;
    bool have = (j + 4 <= j1);
    if (have) { e0 = E[j]; e1 = E[j + 1]; e2 = E[j + 2]; e3 = E[j + 3]; }
    while (have) {
        int jn = j + 4;
        bool haveN = (jn + 4 <= j1);
        float2 p0 = p[e0.x], p1 = p[e1.x], p2 = p[e2.x], p3 = p[e3.x];
        int2 n0, n1, n2, n3;
        if (haveN) { n0 = E[jn]; n1 = E[jn + 1]; n2 = E[jn + 2]; n3 = E[jn + 3]; }
        float h0 = fmaxf(fmaf(p0.x, wr, fmaf(p0.y, wo, bb)), 0.0f);
        float h1v = fmaxf(fmaf(p1.x, wr, fmaf(p1.y, wo, bb)), 0.0f);
        float h2v = fmaxf(fmaf(p2.x, wr, fmaf(p2.y, wo, bb)), 0.0f);
        float h3v = fmaxf(fmaf(p3.x, wr, fmaf(p3.y, wo, bb)), 0.0f);
        acc = fmaf(__int_as_float(e0.y), h0, acc);
        acc = fmaf(__int_as_float(e1.y), h1v, acc);
        acc = fmaf(__int_as_float(e2.y), h2v, acc);
        acc = fmaf(__int_as_float(e3.y), h3v, acc);
        e0 = n0; e1 = n1; e2 = n2; e3 = n3;
        j = jn; have = haveN;
    }
    for (; j < j1; ++j) {
        int2 e = E[j];
        float2 pv = p[e.x];
        float hv = fmaxf(fmaf(pv.x, wr, fmaf(pv.y, wo, bb)), 0.0f);
        acc = fmaf(__int_as_float(e.y), hv, acc);
    }
    agg[node * 64 + c] = acc;
}

// ---------------------------------------------------------------------------
// Layer-3 aggregation: gather bf16 rows (128B/edge). 4-deep pipelined.
__global__ __launch_bounds__(256) void k_gather_bf16(
    const int* __restrict__ rp, const int2* __restrict__ E,
    const unsigned short* __restrict__ h2, float* __restrict__ agg)
{
    int t = blockIdx.x * 256 + threadIdx.x;
    int node = t >> 6, c = t & 63;
    if (node >= N_NODES) return;
    int j0 = rp[node], j1 = rp[node + 1];
    float acc = 0.0f;
    int j = j0;
    int2 e0, e1, e2, e3;
    bool have = (j + 4 <= j1);
    if (have) { e0 = E[j]; e1 = E[j + 1]; e2 = E[j + 2]; e3 = E[j + 3]; }
    while (have) {
        int jn = j + 4;
        bool haveN = (jn + 4 <= j1);
        float v0 = bfu(h2[e0.x * 64 + c]);
        float v1 = bfu(h2[e1.x * 64 + c]);
        float v2 = bfu(h2[e2.x * 64 + c]);
        float v3 = bfu(h2[e3.x * 64 + c]);
        int2 n0, n1, n2, n3;
        if (haveN) { n0 = E[jn]; n1 = E[jn + 1]; n2 = E[jn + 2]; n3 = E[jn + 3]; }
        acc = fmaf(__int_as_float(e0.y), v0, acc);
        acc = fmaf(__int_as_float(e1.y), v1, acc);
        acc = fmaf(__int_as_float(e2.y), v2, acc);
        acc = fmaf(__int_as_float(e3.y), v3, acc);
        e0 = n0; e1 = n1; e2 = n2; e3 = n3;
        j = jn; have = haveN;
    }
    for (; j < j1; ++j) {
        int2 e = E[j];
        acc = fmaf(__int_as_float(e.y), bfu(h2[e.x * 64 + c]), acc);
    }
    agg[node * 64 + c] = acc;
}

// ---------------------------------------------------------------------------
// Transform 2: h2 = relu(agg2 @ Wrel2^T + b2 + h1 @ Wroot2^T), h1 recomputed
// from pair p. Weights register-resident per lane; cross-lane via v_readlane.
__global__ __launch_bounds__(256) void k_transform2(
    const float* __restrict__ agg, const float2* __restrict__ p,
    const float* __restrict__ Wrel, const float* __restrict__ brel,
    const float* __restrict__ Wroot,
    const float* __restrict__ Wr1, const float* __restrict__ b1,
    const float* __restrict__ Wo1,
    unsigned short* __restrict__ h2)
{
    int t = threadIdx.x;
    int wv = t >> 6, c = t & 63;
    float rR[64], rO[64];
    #pragma unroll
    for (int q = 0; q < 16; ++q) {
        float4 a = ((const float4*)(Wrel + c * 64))[q];
        rR[4 * q + 0] = a.x; rR[4 * q + 1] = a.y; rR[4 * q + 2] = a.z; rR[4 * q + 3] = a.w;
        float4 b = ((const float4*)(Wroot + c * 64))[q];
        rO[4 * q + 0] = b.x; rO[4 * q + 1] = b.y; rO[4 * q + 2] = b.z; rO[4 * q + 3] = b.w;
    }
    float bc = brel[c];
    float wr1 = Wr1[c], bb1 = b1[c], wo1 = Wo1[c];
    int gw = blockIdx.x * 4 + wv;
    int nw = gridDim.x * 4;
    for (int i = gw; i < N_NODES; i += nw) {
        float av = agg[i * 64 + c];
        float2 pv = p[i];
        float hv = fmaxf(fmaf(pv.x, wr1, fmaf(pv.y, wo1, bb1)), 0.0f);
        float acc = bc;
        #pragma unroll
        for (int k = 0; k < 64; ++k) {
            acc = fmaf(lane_bcast(av, k), rR[k], acc);
            acc = fmaf(lane_bcast(hv, k), rO[k], acc);
        }
        acc = fmaxf(acc, 0.0f);
        h2[i * 64 + c] = f2bf(acc);
    }
}

// Transform 3 (no relu): h3 = agg3 @ Wrel3^T + b3 + h2 @ Wroot3^T, in-place on agg.
__global__ __launch_bounds__(256) void k_transform3(
    float* __restrict__ agg, const unsigned short* __restrict__ h2,
    const float* __restrict__ Wrel, const float* __restrict__ brel,
    const float* __restrict__ Wroot)
{
    int t = threadIdx.x;
    int wv = t >> 6, c = t & 63;
    float rR[64], rO[64];
    #pragma unroll
    for (int q = 0; q < 16; ++q) {
        float4 a = ((const float4*)(Wrel + c * 64))[q];
        rR[4 * q + 0] = a.x; rR[4 * q + 1] = a.y; rR[4 * q + 2] = a.z; rR[4 * q + 3] = a.w;
        float4 b = ((const float4*)(Wroot + c * 64))[q];
        rO[4 * q + 0] = b.x; rO[4 * q + 1] = b.y; rO[4 * q + 2] = b.z; rO[4 * q + 3] = b.w;
    }
    float bc = brel[c];
    int gw = blockIdx.x * 4 + wv;
    int nw = gridDim.x * 4;
    for (int i = gw; i < N_NODES; i += nw) {
        float av = agg[i * 64 + c];
        float hv = bfu(h2[i * 64 + c]);
        float acc = bc;
        #pragma unroll
        for (int k = 0; k < 64; ++k) {
            acc = fmaf(lane_bcast(av, k), rR[k], acc);
            acc = fmaf(lane_bcast(hv, k), rO[k], acc);
        }
        agg[i * 64 + c] = acc;
    }
}

// ---------------------------------------------------------------------------
// Mean-pool per graph + final 64->16 linear. One block per graph.
__global__ __launch_bounds__(256) void k_pool(
    const float* __restrict__ h, const int* __restrict__ batch,
    const float* __restrict__ Wlin, const float* __restrict__ blin,
    float* __restrict__ out)
{
    int g = blockIdx.x;
    int t = threadIdx.x;
    int c = t & 63, seg = t >> 6;

    int lo = 0, hi = N_NODES;
    while (lo < hi) { int mid = (lo + hi) >> 1; if (batch[mid] < g) lo = mid + 1; else hi = mid; }
    int s0 = lo;
    lo = 0; hi = N_NODES;
    while (lo < hi) { int mid = (lo + hi) >> 1; if (batch[mid] < g + 1) lo = mid + 1; else hi = mid; }
    int s1 = lo;

    __shared__ float sums[256];
    float acc = 0.0f;
    for (int i = s0 + seg; i < s1; i += 4) acc += h[i * 64 + c];
    sums[t] = acc;
    __syncthreads();
    if (t < 64) {
        float v = sums[t] + sums[t + 64] + sums[t + 128] + sums[t + 192];
        float cnt = (float)(s1 - s0);
        sums[t] = v / fmaxf(cnt, 1.0f);
    }
    __syncthreads();
    if (t < OUT_CH) {
        float acc2 = blin[t];
        #pragma unroll 8
        for (int k = 0; k < HIDDEN; ++k) acc2 += sums[k] * Wlin[t * 64 + k];
        out[g * OUT_CH + t] = acc2;
    }
}

// ---------------------------------------------------------------------------
extern "C" void kernel_launch(void* const* d_in, const int* in_sizes, int n_in,
                              void* d_out, int out_size, void* d_ws, size_t ws_size,
                              hipStream_t stream)
{
    const float* x    = (const float*)d_in[0];
    const int*   ei   = (const int*)d_in[1];      // [2, E]: row0=src, row1=dst
    const int*   src  = ei;
    const int*   dst  = ei + N_EDGES;
    const float* ew   = (const float*)d_in[2];
    const int*   batch= (const int*)d_in[3];
    const float* Wr1  = (const float*)d_in[4];
    const float* b1   = (const float*)d_in[5];
    const float* Wo1  = (const float*)d_in[6];
    const float* Wr2  = (const float*)d_in[7];
    const float* b2   = (const float*)d_in[8];
    const float* Wo2  = (const float*)d_in[9];
    const float* Wr3  = (const float*)d_in[10];
    const float* b3   = (const float*)d_in[11];
    const float* Wo3  = (const float*)d_in[12];
    const float* Wlin = (const float*)d_in[13];
    const float* blin = (const float*)d_in[14];
    float* out = (float*)d_out;

    // workspace layout (66 MB max proven safe)
    char* ws = (char*)d_ws;
    const size_t K = 1024;
    int*            row_ptr = (int*)(ws + 0);             // 400 KB
    int*            cursor  = (int*)(ws + 512 * K);       // 400 KB (doubles as cnt)
    int*            bsum    = (int*)(ws + 1024 * K);
    int*            boff    = (int*)(ws + 1032 * K);
    float2*         p       = (float2*)(ws + 1280 * K);   // 800 KB
    int2*           E       = (int2*)(ws + 4096 * K);     // 12.8 MB
    unsigned short* h2      = (unsigned short*)(ws + 17408 * K); // 12.8 MB
    float*          aggbuf  = (float*)(ws + 30720 * K);   // 25.6 MB

    // ---- CSR build (bucket edges by dst) ----
    hipMemsetAsync(cursor, 0, N_NODES * sizeof(int), stream);
    k_hist<<<N_EDGES / 256, 256, 0, stream>>>(dst, cursor);
    k_partial<<<NB1, SCAN_B, 0, stream>>>(cursor, bsum);
    k_scan_bsum<<<1, 512, 0, stream>>>(bsum, boff);
    k_scan_final<<<NB1, SCAN_B, 0, stream>>>(cursor, boff, row_ptr, cursor);
    k_scatter<<<N_EDGES / 256, 256, 0, stream>>>(src, dst, ew, cursor, E);

    // ---- layer 1 (C=1): agg + pack pair (agg1, x) ----
    k_agg1_pair<<<NB1, 256, 0, stream>>>(row_ptr, E, x, p);

    // ---- layer 2: gather from pairs, transform -> h2 (bf16) ----
    k_gather_pair<<<(N_NODES * 64) / 256, 256, 0, stream>>>(row_ptr, E, p, Wr1, b1, Wo1, aggbuf);
    k_transform2<<<1024, 256, 0, stream>>>(aggbuf, p, Wr2, b2, Wo2, Wr1, b1, Wo1, h2);

    // ---- layer 3: gather bf16 rows, transform in-place -> h3 (f32) ----
    k_gather_bf16<<<(N_NODES * 64) / 256, 256, 0, stream>>>(row_ptr, E, h2, aggbuf);
    k_transform3<<<1024, 256, 0, stream>>>(aggbuf, h2, Wr3, b3, Wo3);

    // ---- pool + linear ----
    k_pool<<<N_GRAPHS, 256, 0, stream>>>(aggbuf, batch, Wlin, blin, out);
}

// Round 4
// 661.615 us; speedup vs baseline: 4.9486x; 1.0099x over previous
//
#include <hip/hip_runtime.h>

#define N_NODES 100000
#define N_EDGES 1600000
#define HIDDEN 64
#define OUT_CH 16
#define N_GRAPHS 64
#define SCAN_B 256
#define NB1 ((N_NODES + SCAN_B - 1) / SCAN_B)   // 391 scan blocks
#define W_SCALE (1.0f / 32767.0f)

__device__ __forceinline__ float lane_bcast(float v, int l) {
    return __uint_as_float(__builtin_amdgcn_readlane(__float_as_uint(v), l));
}
__device__ __forceinline__ float bfu(unsigned short u) {            // bf16 -> f32
    return __uint_as_float(((unsigned)u) << 16);
}
__device__ __forceinline__ unsigned short f2bf(float x) {           // f32 -> bf16 RTN
    unsigned u = __float_as_uint(x);
    return (unsigned short)((u + 0x7FFFu + ((u >> 16) & 1u)) >> 16);
}

// ---------------------------------------------------------------------------
// CSR build step 1: histogram of dst + pack edge payload pe = (src<<15)|w15
__global__ __launch_bounds__(256) void k_hist_pack(
    const int* __restrict__ src, const int* __restrict__ dst,
    const float* __restrict__ w, int* __restrict__ cnt,
    unsigned* __restrict__ pe)
{
    int e = blockIdx.x * 256 + threadIdx.x;
    if (e < N_EDGES) {
        atomicAdd(&cnt[dst[e]], 1);
        int q = __float2int_rn(w[e] * 32767.0f);
        pe[e] = ((unsigned)src[e] << 15) | (unsigned)q;
    }
}

// step 2a: per-block sums of PADDED counts (rows padded to multiple of 4)
__global__ __launch_bounds__(SCAN_B) void k_partial(const int* __restrict__ cnt, int* __restrict__ bsum) {
    __shared__ int s[SCAN_B];
    int b = blockIdx.x, t = threadIdx.x;
    int i = b * SCAN_B + t;
    s[t] = (i < N_NODES) ? ((cnt[i] + 3) & ~3) : 0;
    __syncthreads();
    for (int off = SCAN_B / 2; off > 0; off >>= 1) {
        if (t < off) s[t] += s[t + off];
        __syncthreads();
    }
    if (t == 0) bsum[b] = s[0];
}

// step 2b: exclusive scan of the 391 block sums (single block)
__global__ __launch_bounds__(512) void k_scan_bsum(const int* __restrict__ bsum, int* __restrict__ boff) {
    __shared__ int s[512];
    int t = threadIdx.x;
    int v = (t < NB1) ? bsum[t] : 0;
    s[t] = v;
    __syncthreads();
    for (int off = 1; off < 512; off <<= 1) {
        int x = (t >= off) ? s[t - off] : 0;
        __syncthreads();
        s[t] += x;
        __syncthreads();
    }
    if (t < NB1) boff[t] = s[t] - v;   // exclusive
}

// step 2c: per-block exclusive scan of padded counts -> row_ptr; init cursor
__global__ __launch_bounds__(SCAN_B) void k_scan_final(const int* __restrict__ cnt, const int* __restrict__ boff,
                                                       int* __restrict__ row_ptr, int* __restrict__ cursor) {
    __shared__ int s[SCAN_B];
    int b = blockIdx.x, t = threadIdx.x;
    int i = b * SCAN_B + t;
    int v = (i < N_NODES) ? ((cnt[i] + 3) & ~3) : 0;
    s[t] = v;
    __syncthreads();
    for (int off = 1; off < SCAN_B; off <<= 1) {
        int x = (t >= off) ? s[t - off] : 0;
        __syncthreads();
        s[t] += x;
        __syncthreads();
    }
    if (i < N_NODES) {
        int rp = boff[b] + s[t] - v;
        row_ptr[i] = rp;
        cursor[i] = rp;
        if (i == N_NODES - 1) row_ptr[N_NODES] = boff[b] + s[t];  // total padded
    }
}

// step 3: scatter packed 4B entries into (pre-zeroed, padded) CSR order
__global__ __launch_bounds__(256) void k_scatter(const int* __restrict__ dst, const unsigned* __restrict__ pe,
                                                 int* __restrict__ cursor, unsigned* __restrict__ E) {
    int e = blockIdx.x * 256 + threadIdx.x;
    if (e < N_EDGES) {
        int pos = atomicAdd(&cursor[dst[e]], 1);
        E[pos] = pe[e];
    }
}

// ---------------------------------------------------------------------------
// Layer 1 (C=1) aggregation + pair pack: p[i] = (agg1[i], x[i])
__global__ __launch_bounds__(256) void k_agg1_pair(const int* __restrict__ rp, const unsigned* __restrict__ E,
                                                   const float* __restrict__ x, float2* __restrict__ p) {
    int i = blockIdx.x * 256 + threadIdx.x;
    if (i >= N_NODES) return;
    int j1 = rp[i + 1];
    float acc = 0.0f;
    for (int j = rp[i]; j < j1; ++j) {
        unsigned e = E[j];
        acc = fmaf((float)(e & 32767u) * W_SCALE, x[e >> 15], acc);
    }
    p[i] = make_float2(acc, x[i]);
}

// ---------------------------------------------------------------------------
// Layer-2 aggregation: gather 8B pairs (L2-resident), reconstruct h1[s][c]
// in-lane. One wave per node, lane = channel. 4 edges per int4 broadcast load.
__global__ __launch_bounds__(256) void k_gather_pair(
    const int* __restrict__ rp, const unsigned* __restrict__ E,
    const float2* __restrict__ p,
    const float* __restrict__ Wr1, const float* __restrict__ b1,
    const float* __restrict__ Wo1, float* __restrict__ agg)
{
    int t = blockIdx.x * 256 + threadIdx.x;
    int node = t >> 6, c = t & 63;
    if (node >= N_NODES) return;
    float wr = Wr1[c], bb = b1[c], wo = Wo1[c];
    int j0 = rp[node], j1 = rp[node + 1];
    const uint4* E4 = (const uint4*)E;
    float acc = 0.0f;
    for (int j4 = (j0 >> 2); j4 < (j1 >> 2); ++j4) {
        uint4 e = E4[j4];
        float2 p0 = p[e.x >> 15];
        float2 p1 = p[e.y >> 15];
        float2 p2 = p[e.z >> 15];
        float2 p3 = p[e.w >> 15];
        float w0 = (float)(e.x & 32767u) * W_SCALE;
        float w1 = (float)(e.y & 32767u) * W_SCALE;
        float w2 = (float)(e.z & 32767u) * W_SCALE;
        float w3 = (float)(e.w & 32767u) * W_SCALE;
        acc = fmaf(w0, fmaxf(fmaf(p0.x, wr, fmaf(p0.y, wo, bb)), 0.0f), acc);
        acc = fmaf(w1, fmaxf(fmaf(p1.x, wr, fmaf(p1.y, wo, bb)), 0.0f), acc);
        acc = fmaf(w2, fmaxf(fmaf(p2.x, wr, fmaf(p2.y, wo, bb)), 0.0f), acc);
        acc = fmaf(w3, fmaxf(fmaf(p3.x, wr, fmaf(p3.y, wo, bb)), 0.0f), acc);
    }
    agg[node * 64 + c] = acc;
}

// ---------------------------------------------------------------------------
// Layer-3 aggregation, grouped: 16 lanes per row, lane group g = lane>>4 owns
// edge j+g; each lane loads ushort4 (4 bf16 channels, 8B) -> one load instr
// fetches 4 edges' rows. 2-deep E prefetch. Butterfly reduce + float4 store.
__global__ __launch_bounds__(256) void k_gather_bf16(
    const int* __restrict__ rp, const unsigned* __restrict__ E,
    const unsigned short* __restrict__ h2, float* __restrict__ agg)
{
    int t = blockIdx.x * 256 + threadIdx.x;
    int node = t >> 6;
    int l = t & 63;
    int g = l >> 4, q = l & 15;
    if (node >= N_NODES) return;
    int j0 = rp[node], j1 = rp[node + 1];
    float4 acc = make_float4(0.0f, 0.0f, 0.0f, 0.0f);
    int j = j0;
    unsigned ec = (j < j1) ? E[j + g] : 0u;
    while (j < j1) {
        int jn = j + 4;
        unsigned src = ec >> 15;
        float wq = (float)(ec & 32767u) * W_SCALE;
        ushort4 rv = *((const ushort4*)(h2 + src * 64) + q);
        unsigned en = (jn < j1) ? E[jn + g] : 0u;
        acc.x = fmaf(wq, bfu(rv.x), acc.x);
        acc.y = fmaf(wq, bfu(rv.y), acc.y);
        acc.z = fmaf(wq, bfu(rv.z), acc.z);
        acc.w = fmaf(wq, bfu(rv.w), acc.w);
        ec = en; j = jn;
    }
    // sum partials across the 4 lane groups (xor 16, then 32)
    acc.x += __shfl_xor(acc.x, 16); acc.y += __shfl_xor(acc.y, 16);
    acc.z += __shfl_xor(acc.z, 16); acc.w += __shfl_xor(acc.w, 16);
    acc.x += __shfl_xor(acc.x, 32); acc.y += __shfl_xor(acc.y, 32);
    acc.z += __shfl_xor(acc.z, 32); acc.w += __shfl_xor(acc.w, 32);
    if (l < 16) ((float4*)(agg + node * 64))[q] = acc;
}

// ---------------------------------------------------------------------------
// Transform 2: h2 = relu(agg2 @ Wrel2^T + b2 + h1 @ Wroot2^T), h1 recomputed
// from pair p. Weights register-resident per lane; cross-lane via v_readlane.
__global__ __launch_bounds__(256) void k_transform2(
    const float* __restrict__ agg, const float2* __restrict__ p,
    const float* __restrict__ Wrel, const float* __restrict__ brel,
    const float* __restrict__ Wroot,
    const float* __restrict__ Wr1, const float* __restrict__ b1,
    const float* __restrict__ Wo1,
    unsigned short* __restrict__ h2)
{
    int t = threadIdx.x;
    int wv = t >> 6, c = t & 63;
    float rR[64], rO[64];
    #pragma unroll
    for (int q = 0; q < 16; ++q) {
        float4 a = ((const float4*)(Wrel + c * 64))[q];
        rR[4 * q + 0] = a.x; rR[4 * q + 1] = a.y; rR[4 * q + 2] = a.z; rR[4 * q + 3] = a.w;
        float4 b = ((const float4*)(Wroot + c * 64))[q];
        rO[4 * q + 0] = b.x; rO[4 * q + 1] = b.y; rO[4 * q + 2] = b.z; rO[4 * q + 3] = b.w;
    }
    float bc = brel[c];
    float wr1 = Wr1[c], bb1 = b1[c], wo1 = Wo1[c];
    int gw = blockIdx.x * 4 + wv;
    int nw = gridDim.x * 4;
    for (int i = gw; i < N_NODES; i += nw) {
        float av = agg[i * 64 + c];
        float2 pv = p[i];
        float hv = fmaxf(fmaf(pv.x, wr1, fmaf(pv.y, wo1, bb1)), 0.0f);
        float acc = bc;
        #pragma unroll
        for (int k = 0; k < 64; ++k) {
            acc = fmaf(lane_bcast(av, k), rR[k], acc);
            acc = fmaf(lane_bcast(hv, k), rO[k], acc);
        }
        acc = fmaxf(acc, 0.0f);
        h2[i * 64 + c] = f2bf(acc);
    }
}

// Transform 3 (no relu): h3 = agg3 @ Wrel3^T + b3 + h2 @ Wroot3^T, in-place on agg.
__global__ __launch_bounds__(256) void k_transform3(
    float* __restrict__ agg, const unsigned short* __restrict__ h2,
    const float* __restrict__ Wrel, const float* __restrict__ brel,
    const float* __restrict__ Wroot)
{
    int t = threadIdx.x;
    int wv = t >> 6, c = t & 63;
    float rR[64], rO[64];
    #pragma unroll
    for (int q = 0; q < 16; ++q) {
        float4 a = ((const float4*)(Wrel + c * 64))[q];
        rR[4 * q + 0] = a.x; rR[4 * q + 1] = a.y; rR[4 * q + 2] = a.z; rR[4 * q + 3] = a.w;
        float4 b = ((const float4*)(Wroot + c * 64))[q];
        rO[4 * q + 0] = b.x; rO[4 * q + 1] = b.y; rO[4 * q + 2] = b.z; rO[4 * q + 3] = b.w;
    }
    float bc = brel[c];
    int gw = blockIdx.x * 4 + wv;
    int nw = gridDim.x * 4;
    for (int i = gw; i < N_NODES; i += nw) {
        float av = agg[i * 64 + c];
        float hv = bfu(h2[i * 64 + c]);
        float acc = bc;
        #pragma unroll
        for (int k = 0; k < 64; ++k) {
            acc = fmaf(lane_bcast(av, k), rR[k], acc);
            acc = fmaf(lane_bcast(hv, k), rO[k], acc);
        }
        agg[i * 64 + c] = acc;
    }
}

// ---------------------------------------------------------------------------
// Mean-pool per graph + final 64->16 linear. One block per graph.
__global__ __launch_bounds__(256) void k_pool(
    const float* __restrict__ h, const int* __restrict__ batch,
    const float* __restrict__ Wlin, const float* __restrict__ blin,
    float* __restrict__ out)
{
    int g = blockIdx.x;
    int t = threadIdx.x;
    int c = t & 63, seg = t >> 6;

    int lo = 0, hi = N_NODES;
    while (lo < hi) { int mid = (lo + hi) >> 1; if (batch[mid] < g) lo = mid + 1; else hi = mid; }
    int s0 = lo;
    lo = 0; hi = N_NODES;
    while (lo < hi) { int mid = (lo + hi) >> 1; if (batch[mid] < g + 1) lo = mid + 1; else hi = mid; }
    int s1 = lo;

    __shared__ float sums[256];
    float acc = 0.0f;
    for (int i = s0 + seg; i < s1; i += 4) acc += h[i * 64 + c];
    sums[t] = acc;
    __syncthreads();
    if (t < 64) {
        float v = sums[t] + sums[t + 64] + sums[t + 128] + sums[t + 192];
        float cnt = (float)(s1 - s0);
        sums[t] = v / fmaxf(cnt, 1.0f);
    }
    __syncthreads();
    if (t < OUT_CH) {
        float acc2 = blin[t];
        #pragma unroll 8
        for (int k = 0; k < HIDDEN; ++k) acc2 += sums[k] * Wlin[t * 64 + k];
        out[g * OUT_CH + t] = acc2;
    }
}

// ---------------------------------------------------------------------------
extern "C" void kernel_launch(void* const* d_in, const int* in_sizes, int n_in,
                              void* d_out, int out_size, void* d_ws, size_t ws_size,
                              hipStream_t stream)
{
    const float* x    = (const float*)d_in[0];
    const int*   ei   = (const int*)d_in[1];      // [2, E]: row0=src, row1=dst
    const int*   src  = ei;
    const int*   dst  = ei + N_EDGES;
    const float* ew   = (const float*)d_in[2];
    const int*   batch= (const int*)d_in[3];
    const float* Wr1  = (const float*)d_in[4];
    const float* b1   = (const float*)d_in[5];
    const float* Wo1  = (const float*)d_in[6];
    const float* Wr2  = (const float*)d_in[7];
    const float* b2   = (const float*)d_in[8];
    const float* Wo2  = (const float*)d_in[9];
    const float* Wr3  = (const float*)d_in[10];
    const float* b3   = (const float*)d_in[11];
    const float* Wo3  = (const float*)d_in[12];
    const float* Wlin = (const float*)d_in[13];
    const float* blin = (const float*)d_in[14];
    float* out = (float*)d_out;

    // workspace layout (~54 MB; 66+ MB proven safe earlier)
    char* ws = (char*)d_ws;
    const size_t K = 1024;
    int*            row_ptr = (int*)(ws + 0);              // 400 KB
    int*            cursor  = (int*)(ws + 512 * K);        // 400 KB (doubles as cnt)
    int*            bsum    = (int*)(ws + 1024 * K);
    int*            boff    = (int*)(ws + 1032 * K);
    float2*         p       = (float2*)(ws + 1280 * K);    // 800 KB
    unsigned*       pe      = (unsigned*)(ws + 2176 * K);  // 6.4 MB (packed, edge order)
    unsigned*       E       = (unsigned*)(ws + 8704 * K);  // up to 7.6 MB (padded CSR)
    unsigned short* h2      = (unsigned short*)(ws + 16384 * K); // 12.8 MB
    float*          aggbuf  = (float*)(ws + 29696 * K);    // 25.6 MB

    // ---- CSR build (bucket edges by dst; rows padded to x4, pads = zeros) ----
    hipMemsetAsync(cursor, 0, N_NODES * sizeof(int), stream);
    hipMemsetAsync(E, 0, 7800 * K, stream);
    k_hist_pack<<<N_EDGES / 256, 256, 0, stream>>>(src, dst, ew, cursor, pe);
    k_partial<<<NB1, SCAN_B, 0, stream>>>(cursor, bsum);
    k_scan_bsum<<<1, 512, 0, stream>>>(bsum, boff);
    k_scan_final<<<NB1, SCAN_B, 0, stream>>>(cursor, boff, row_ptr, cursor);
    k_scatter<<<N_EDGES / 256, 256, 0, stream>>>(dst, pe, cursor, E);

    // ---- layer 1 (C=1): agg + pack pair (agg1, x) ----
    k_agg1_pair<<<NB1, 256, 0, stream>>>(row_ptr, E, x, p);

    // ---- layer 2: gather from pairs, transform -> h2 (bf16) ----
    k_gather_pair<<<(N_NODES * 64) / 256, 256, 0, stream>>>(row_ptr, E, p, Wr1, b1, Wo1, aggbuf);
    k_transform2<<<1024, 256, 0, stream>>>(aggbuf, p, Wr2, b2, Wo2, Wr1, b1, Wo1, h2);

    // ---- layer 3: gather bf16 rows (grouped), transform in-place -> h3 (f32) ----
    k_gather_bf16<<<(N_NODES * 64) / 256, 256, 0, stream>>>(row_ptr, E, h2, aggbuf);
    k_transform3<<<1024, 256, 0, stream>>>(aggbuf, h2, Wr3, b3, Wo3);

    // ---- pool + linear ----
    k_pool<<<N_GRAPHS, 256, 0, stream>>>(aggbuf, batch, Wlin, blin, out);
}

// Round 7
// 513.176 us; speedup vs baseline: 6.3801x; 1.2893x over previous
//
#include <hip/hip_runtime.h>

#define N_NODES 100000
#define N_EDGES 1600000
#define HIDDEN 64
#define OUT_CH 16
#define N_GRAPHS 64
#define SCAN_B 256
#define NB1 391                       // scan blocks; also NBUCK (100096/256)
#define NBUCK 391                     // coarse buckets (dst >> 8)
#define NN2 (NBUCK * 256)             // 100096: padded node space
#define CBLK 250                      // coarse blocks
#define EPB 6400                      // edges per coarse block (250*6400 = 1.6M)
#define W_SCALE (1.0f / 32767.0f)

__device__ __forceinline__ float lane_bcast(float v, int l) {
    return __uint_as_float(__builtin_amdgcn_readlane(__float_as_uint(v), l));
}
__device__ __forceinline__ float bfu(unsigned short u) {            // bf16 -> f32
    return __uint_as_float(((unsigned)u) << 16);
}
__device__ __forceinline__ unsigned short f2bf(float x) {           // f32 -> bf16 RTN
    unsigned u = __float_as_uint(x);
    return (unsigned short)((u + 0x7FFFu + ((u >> 16) & 1u)) >> 16);
}

// ---------------------------------------------------------------------------
// Phase A1: per-block coarse-bucket histogram (LDS) -> bmat[b][blk]
__global__ __launch_bounds__(256) void k_bhist(const int* __restrict__ dst, int* __restrict__ bmat) {
    __shared__ int bh[NBUCK];
    int t = threadIdx.x, blk = blockIdx.x;
    for (int b = t; b < NBUCK; b += 256) bh[b] = 0;
    __syncthreads();
    int base = blk * EPB;
    for (int r = 0; r < EPB / 256; ++r)
        atomicAdd(&bh[dst[base + r * 256 + t] >> 8], 1);
    __syncthreads();
    for (int b = t; b < NBUCK; b += 256) bmat[b * 256 + blk] = bh[b];
}

// Phase A2: per-bucket exclusive scan over the 250 block counts (column scan)
__global__ __launch_bounds__(256) void k_colscan(int* __restrict__ bmat, int* __restrict__ btotal) {
    __shared__ int s[256];
    int b = blockIdx.x, t = threadIdx.x;
    int v = (t < CBLK) ? bmat[b * 256 + t] : 0;
    s[t] = v;
    __syncthreads();
    for (int off = 1; off < 256; off <<= 1) {
        int x = (t >= off) ? s[t - off] : 0;
        __syncthreads();
        s[t] += x;
        __syncthreads();
    }
    if (t < CBLK) bmat[b * 256 + t] = s[t] - v;   // exclusive within column
    if (t == 255) btotal[b] = s[255];
}

// Generic 391-length exclusive scan in one block (used for cbase and boff)
__global__ __launch_bounds__(512) void k_scan_bsum(const int* __restrict__ in, int* __restrict__ outp) {
    __shared__ int s[512];
    int t = threadIdx.x;
    int v = (t < NB1) ? in[t] : 0;
    s[t] = v;
    __syncthreads();
    for (int off = 1; off < 512; off <<= 1) {
        int x = (t >= off) ? s[t - off] : 0;
        __syncthreads();
        s[t] += x;
        __syncthreads();
    }
    if (t < NB1) outp[t] = s[t] - v;   // exclusive
}

// Phase A3: coarse scatter. Each (block,bucket) owns an exclusive contiguous
// run in C -> writes are short contiguous runs (L2 merges within one XCD).
__global__ __launch_bounds__(256) void k_coarse(
    const int* __restrict__ src, const int* __restrict__ dst, const float* __restrict__ w,
    const int* __restrict__ bmat, const int* __restrict__ cbase, uint2* __restrict__ C)
{
    __shared__ int cur[NBUCK];
    int t = threadIdx.x, blk = blockIdx.x;
    for (int b = t; b < NBUCK; b += 256) cur[b] = cbase[b] + bmat[b * 256 + blk];
    __syncthreads();
    int base = blk * EPB;
    for (int r = 0; r < EPB / 256; ++r) {
        int e = base + r * 256 + t;
        int d = dst[e];
        int q = __float2int_rn(w[e] * 32767.0f);
        unsigned pe = ((unsigned)src[e] << 15) | (unsigned)q;
        int pos = atomicAdd(&cur[d >> 8], 1);
        C[pos] = make_uint2(pe, (unsigned)(d & 255));
    }
}

// Phase B1: per-node counts within each bucket (coalesced region read)
__global__ __launch_bounds__(256) void k_fhist(const uint2* __restrict__ C, const int* __restrict__ cbase,
                                               const int* __restrict__ btotal, int* __restrict__ pcnt) {
    __shared__ int c[256];
    int b = blockIdx.x, t = threadIdx.x;
    c[t] = 0;
    __syncthreads();
    int j0 = cbase[b], j1 = j0 + btotal[b];
    for (int j = j0 + t; j < j1; j += 256) atomicAdd(&c[C[j].y], 1);
    __syncthreads();
    pcnt[b * 256 + t] = c[t];
}

// Phase B2a: per-block sums of PADDED counts (rows padded to multiple of 4)
__global__ __launch_bounds__(SCAN_B) void k_partial(const int* __restrict__ pcnt, int* __restrict__ bsum) {
    __shared__ int s[SCAN_B];
    int b = blockIdx.x, t = threadIdx.x;
    s[t] = (pcnt[b * SCAN_B + t] + 3) & ~3;
    __syncthreads();
    for (int off = SCAN_B / 2; off > 0; off >>= 1) {
        if (t < off) s[t] += s[t + off];
        __syncthreads();
    }
    if (t == 0) bsum[b] = s[0];
}

// Phase B2b: per-block exclusive scan of padded counts -> row_ptr
__global__ __launch_bounds__(SCAN_B) void k_scan_final(const int* __restrict__ pcnt, const int* __restrict__ boff,
                                                       int* __restrict__ row_ptr) {
    __shared__ int s[SCAN_B];
    int b = blockIdx.x, t = threadIdx.x;
    int i = b * SCAN_B + t;
    int v = (pcnt[i] + 3) & ~3;
    s[t] = v;
    __syncthreads();
    for (int off = 1; off < SCAN_B; off <<= 1) {
        int x = (t >= off) ? s[t - off] : 0;
        __syncthreads();
        s[t] += x;
        __syncthreads();
    }
    row_ptr[i] = boff[b] + s[t] - v;
    if (i == NN2 - 1) row_ptr[NN2] = boff[b] + s[t];   // padded total
}

// Phase B3: fine scatter. One block per bucket -> E region has a SINGLE
// writer block (one CU / one L2) -> lines merge fully, WRITE ~= payload.
__global__ __launch_bounds__(256) void k_fine(const uint2* __restrict__ C, const int* __restrict__ cbase,
                                              const int* __restrict__ btotal, const int* __restrict__ row_ptr,
                                              unsigned* __restrict__ E) {
    __shared__ int cur[256];
    int b = blockIdx.x, t = threadIdx.x;
    cur[t] = row_ptr[b * 256 + t];
    __syncthreads();
    int j0 = cbase[b], j1 = j0 + btotal[b];
    for (int j = j0 + t; j < j1; j += 256) {
        uint2 c = C[j];
        int pos = atomicAdd(&cur[c.y], 1);
        E[pos] = c.x;
    }
}

// ---------------------------------------------------------------------------
// Layer 1 (C=1) aggregation + pair pack: p[i] = (agg1[i], x[i])
__global__ __launch_bounds__(256) void k_agg1_pair(const int* __restrict__ rp, const unsigned* __restrict__ E,
                                                   const float* __restrict__ x, float2* __restrict__ p) {
    int i = blockIdx.x * 256 + threadIdx.x;
    if (i >= N_NODES) return;
    int j1 = rp[i + 1];
    float acc = 0.0f;
    for (int j = rp[i]; j < j1; ++j) {
        unsigned e = E[j];
        acc = fmaf((float)(e & 32767u) * W_SCALE, x[e >> 15], acc);
    }
    p[i] = make_float2(acc, x[i]);
}

// ---------------------------------------------------------------------------
// Layer-2 aggregation: gather 8B pairs (L2-resident), reconstruct h1[s][c]
// in-lane. One wave per node, lane = channel. 4 edges per int4 broadcast load.
__global__ __launch_bounds__(256) void k_gather_pair(
    const int* __restrict__ rp, const unsigned* __restrict__ E,
    const float2* __restrict__ p,
    const float* __restrict__ Wr1, const float* __restrict__ b1,
    const float* __restrict__ Wo1, float* __restrict__ agg)
{
    int t = blockIdx.x * 256 + threadIdx.x;
    int node = t >> 6, c = t & 63;
    if (node >= N_NODES) return;
    float wr = Wr1[c], bb = b1[c], wo = Wo1[c];
    int j0 = rp[node], j1 = rp[node + 1];
    const uint4* E4 = (const uint4*)E;
    float acc = 0.0f;
    for (int j4 = (j0 >> 2); j4 < (j1 >> 2); ++j4) {
        uint4 e = E4[j4];
        float2 p0 = p[e.x >> 15];
        float2 p1 = p[e.y >> 15];
        float2 p2 = p[e.z >> 15];
        float2 p3 = p[e.w >> 15];
        float w0 = (float)(e.x & 32767u) * W_SCALE;
        float w1 = (float)(e.y & 32767u) * W_SCALE;
        float w2 = (float)(e.z & 32767u) * W_SCALE;
        float w3 = (float)(e.w & 32767u) * W_SCALE;
        acc = fmaf(w0, fmaxf(fmaf(p0.x, wr, fmaf(p0.y, wo, bb)), 0.0f), acc);
        acc = fmaf(w1, fmaxf(fmaf(p1.x, wr, fmaf(p1.y, wo, bb)), 0.0f), acc);
        acc = fmaf(w2, fmaxf(fmaf(p2.x, wr, fmaf(p2.y, wo, bb)), 0.0f), acc);
        acc = fmaf(w3, fmaxf(fmaf(p3.x, wr, fmaf(p3.y, wo, bb)), 0.0f), acc);
    }
    agg[node * 64 + c] = acc;
}

// ---------------------------------------------------------------------------
// Layer-3 aggregation, grouped: 16 lanes per row, lane group g = lane>>4 owns
// edge j+g; each lane loads ushort4 (4 bf16 channels, 8B) -> one load instr
// fetches 4 edges' rows. 2-deep E prefetch. Butterfly reduce + float4 store.
__global__ __launch_bounds__(256) void k_gather_bf16(
    const int* __restrict__ rp, const unsigned* __restrict__ E,
    const unsigned short* __restrict__ h2, float* __restrict__ agg)
{
    int t = blockIdx.x * 256 + threadIdx.x;
    int node = t >> 6;
    int l = t & 63;
    int g = l >> 4, q = l & 15;
    if (node >= N_NODES) return;
    int j0 = rp[node], j1 = rp[node + 1];
    float4 acc = make_float4(0.0f, 0.0f, 0.0f, 0.0f);
    int j = j0;
    unsigned ec = (j < j1) ? E[j + g] : 0u;
    while (j < j1) {
        int jn = j + 4;
        unsigned src = ec >> 15;
        float wq = (float)(ec & 32767u) * W_SCALE;
        ushort4 rv = *((const ushort4*)(h2 + src * 64) + q);
        unsigned en = (jn < j1) ? E[jn + g] : 0u;
        acc.x = fmaf(wq, bfu(rv.x), acc.x);
        acc.y = fmaf(wq, bfu(rv.y), acc.y);
        acc.z = fmaf(wq, bfu(rv.z), acc.z);
        acc.w = fmaf(wq, bfu(rv.w), acc.w);
        ec = en; j = jn;
    }
    acc.x += __shfl_xor(acc.x, 16); acc.y += __shfl_xor(acc.y, 16);
    acc.z += __shfl_xor(acc.z, 16); acc.w += __shfl_xor(acc.w, 16);
    acc.x += __shfl_xor(acc.x, 32); acc.y += __shfl_xor(acc.y, 32);
    acc.z += __shfl_xor(acc.z, 32); acc.w += __shfl_xor(acc.w, 32);
    if (l < 16) ((float4*)(agg + node * 64))[q] = acc;
}

// ---------------------------------------------------------------------------
// Transform 2: h2 = relu(agg2 @ Wrel2^T + b2 + h1 @ Wroot2^T), h1 recomputed
// from pair p. Weights register-resident per lane; cross-lane via v_readlane.
__global__ __launch_bounds__(256) void k_transform2(
    const float* __restrict__ agg, const float2* __restrict__ p,
    const float* __restrict__ Wrel, const float* __restrict__ brel,
    const float* __restrict__ Wroot,
    const float* __restrict__ Wr1, const float* __restrict__ b1,
    const float* __restrict__ Wo1,
    unsigned short* __restrict__ h2)
{
    int t = threadIdx.x;
    int wv = t >> 6, c = t & 63;
    float rR[64], rO[64];
    #pragma unroll
    for (int q = 0; q < 16; ++q) {
        float4 a = ((const float4*)(Wrel + c * 64))[q];
        rR[4 * q + 0] = a.x; rR[4 * q + 1] = a.y; rR[4 * q + 2] = a.z; rR[4 * q + 3] = a.w;
        float4 b = ((const float4*)(Wroot + c * 64))[q];
        rO[4 * q + 0] = b.x; rO[4 * q + 1] = b.y; rO[4 * q + 2] = b.z; rO[4 * q + 3] = b.w;
    }
    float bc = brel[c];
    float wr1 = Wr1[c], bb1 = b1[c], wo1 = Wo1[c];
    int gw = blockIdx.x * 4 + wv;
    int nw = gridDim.x * 4;
    for (int i = gw; i < N_NODES; i += nw) {
        float av = agg[i * 64 + c];
        float2 pv = p[i];
        float hv = fmaxf(fmaf(pv.x, wr1, fmaf(pv.y, wo1, bb1)), 0.0f);
        float acc = bc;
        #pragma unroll
        for (int k = 0; k < 64; ++k) {
            acc = fmaf(lane_bcast(av, k), rR[k], acc);
            acc = fmaf(lane_bcast(hv, k), rO[k], acc);
        }
        acc = fmaxf(acc, 0.0f);
        h2[i * 64 + c] = f2bf(acc);
    }
}

// Transform 3 (no relu): h3 = agg3 @ Wrel3^T + b3 + h2 @ Wroot3^T, in-place on agg.
__global__ __launch_bounds__(256) void k_transform3(
    float* __restrict__ agg, const unsigned short* __restrict__ h2,
    const float* __restrict__ Wrel, const float* __restrict__ brel,
    const float* __restrict__ Wroot)
{
    int t = threadIdx.x;
    int wv = t >> 6, c = t & 63;
    float rR[64], rO[64];
    #pragma unroll
    for (int q = 0; q < 16; ++q) {
        float4 a = ((const float4*)(Wrel + c * 64))[q];
        rR[4 * q + 0] = a.x; rR[4 * q + 1] = a.y; rR[4 * q + 2] = a.z; rR[4 * q + 3] = a.w;
        float4 b = ((const float4*)(Wroot + c * 64))[q];
        rO[4 * q + 0] = b.x; rO[4 * q + 1] = b.y; rO[4 * q + 2] = b.z; rO[4 * q + 3] = b.w;
    }
    float bc = brel[c];
    int gw = blockIdx.x * 4 + wv;
    int nw = gridDim.x * 4;
    for (int i = gw; i < N_NODES; i += nw) {
        float av = agg[i * 64 + c];
        float hv = bfu(h2[i * 64 + c]);
        float acc = bc;
        #pragma unroll
        for (int k = 0; k < 64; ++k) {
            acc = fmaf(lane_bcast(av, k), rR[k], acc);
            acc = fmaf(lane_bcast(hv, k), rO[k], acc);
        }
        agg[i * 64 + c] = acc;
    }
}

// ---------------------------------------------------------------------------
// Mean-pool per graph + final 64->16 linear. One block per graph.
__global__ __launch_bounds__(256) void k_pool(
    const float* __restrict__ h, const int* __restrict__ batch,
    const float* __restrict__ Wlin, const float* __restrict__ blin,
    float* __restrict__ out)
{
    int g = blockIdx.x;
    int t = threadIdx.x;
    int c = t & 63, seg = t >> 6;

    int lo = 0, hi = N_NODES;
    while (lo < hi) { int mid = (lo + hi) >> 1; if (batch[mid] < g) lo = mid + 1; else hi = mid; }
    int s0 = lo;
    lo = 0; hi = N_NODES;
    while (lo < hi) { int mid = (lo + hi) >> 1; if (batch[mid] < g + 1) lo = mid + 1; else hi = mid; }
    int s1 = lo;

    __shared__ float sums[256];
    float acc = 0.0f;
    for (int i = s0 + seg; i < s1; i += 4) acc += h[i * 64 + c];
    sums[t] = acc;
    __syncthreads();
    if (t < 64) {
        float v = sums[t] + sums[t + 64] + sums[t + 128] + sums[t + 192];
        float cnt = (float)(s1 - s0);
        sums[t] = v / fmaxf(cnt, 1.0f);
    }
    __syncthreads();
    if (t < OUT_CH) {
        float acc2 = blin[t];
        #pragma unroll 8
        for (int k = 0; k < HIDDEN; ++k) acc2 += sums[k] * Wlin[t * 64 + k];
        out[g * OUT_CH + t] = acc2;
    }
}

// ---------------------------------------------------------------------------
extern "C" void kernel_launch(void* const* d_in, const int* in_sizes, int n_in,
                              void* d_out, int out_size, void* d_ws, size_t ws_size,
                              hipStream_t stream)
{
    const float* x    = (const float*)d_in[0];
    const int*   ei   = (const int*)d_in[1];      // [2, E]: row0=src, row1=dst
    const int*   src  = ei;
    const int*   dst  = ei + N_EDGES;
    const float* ew   = (const float*)d_in[2];
    const int*   batch= (const int*)d_in[3];
    const float* Wr1  = (const float*)d_in[4];
    const float* b1   = (const float*)d_in[5];
    const float* Wo1  = (const float*)d_in[6];
    const float* Wr2  = (const float*)d_in[7];
    const float* b2   = (const float*)d_in[8];
    const float* Wo2  = (const float*)d_in[9];
    const float* Wr3  = (const float*)d_in[10];
    const float* b3   = (const float*)d_in[11];
    const float* Wo3  = (const float*)d_in[12];
    const float* Wlin = (const float*)d_in[13];
    const float* blin = (const float*)d_in[14];
    float* out = (float*)d_out;

    // workspace layout (~61 MB; 78.6 MB proven safe in round 0)
    char* ws = (char*)d_ws;
    const size_t K = 1024;
    int*            row_ptr = (int*)(ws + 0);               // 404 KB (NN2+1 ints)
    int*            bmat    = (int*)(ws + 512 * K);         // 391*256*4 = 400 KB
    int*            btotal  = (int*)(ws + 1024 * K);        // 1.6 KB
    int*            cbase   = (int*)(ws + 1028 * K);        // 1.6 KB
    int*            bsum    = (int*)(ws + 1032 * K);
    int*            boff    = (int*)(ws + 1036 * K);
    int*            pcnt    = (int*)(ws + 1040 * K);        // 400 KB
    float2*         p       = (float2*)(ws + 1536 * K);     // 800 KB
    uint2*          C       = (uint2*)(ws + 2560 * K);      // 12.8 MB
    unsigned*       E       = (unsigned*)(ws + 15360 * K);  // up to 7.6 MB (padded CSR)
    unsigned short* h2      = (unsigned short*)(ws + 23552 * K); // 12.8 MB
    float*          aggbuf  = (float*)(ws + 36864 * K);     // 25.6 MB

    // ---- CSR build: 3-phase counting sort (no global position atomics) ----
    hipMemsetAsync(E, 0, 7800 * K, stream);                       // padding zeros
    k_bhist<<<CBLK, 256, 0, stream>>>(dst, bmat);
    k_colscan<<<NBUCK, 256, 0, stream>>>(bmat, btotal);
    k_scan_bsum<<<1, 512, 0, stream>>>(btotal, cbase);
    k_coarse<<<CBLK, 256, 0, stream>>>(src, dst, ew, bmat, cbase, C);
    k_fhist<<<NBUCK, 256, 0, stream>>>(C, cbase, btotal, pcnt);
    k_partial<<<NB1, SCAN_B, 0, stream>>>(pcnt, bsum);
    k_scan_bsum<<<1, 512, 0, stream>>>(bsum, boff);
    k_scan_final<<<NB1, SCAN_B, 0, stream>>>(pcnt, boff, row_ptr);
    k_fine<<<NBUCK, 256, 0, stream>>>(C, cbase, btotal, row_ptr, E);

    // ---- layer 1 (C=1): agg + pack pair (agg1, x) ----
    k_agg1_pair<<<NB1, 256, 0, stream>>>(row_ptr, E, x, p);

    // ---- layer 2: gather from pairs, transform -> h2 (bf16) ----
    k_gather_pair<<<(N_NODES * 64) / 256, 256, 0, stream>>>(row_ptr, E, p, Wr1, b1, Wo1, aggbuf);
    k_transform2<<<1024, 256, 0, stream>>>(aggbuf, p, Wr2, b2, Wo2, Wr1, b1, Wo1, h2);

    // ---- layer 3: gather bf16 rows (grouped), transform in-place -> h3 (f32) ----
    k_gather_bf16<<<(N_NODES * 64) / 256, 256, 0, stream>>>(row_ptr, E, h2, aggbuf);
    k_transform3<<<1024, 256, 0, stream>>>(aggbuf, h2, Wr3, b3, Wo3);

    // ---- pool + linear ----
    k_pool<<<N_GRAPHS, 256, 0, stream>>>(aggbuf, batch, Wlin, blin, out);
}

// Round 8
// 422.074 us; speedup vs baseline: 7.7572x; 1.2158x over previous
//
#include <hip/hip_runtime.h>

#define N_NODES 100000
#define N_EDGES 1600000
#define HIDDEN 64
#define OUT_CH 16
#define N_GRAPHS 64
#define SCAN_B 256
#define NB1 391                       // scan blocks; also NBUCK (100096/256)
#define NBUCK 391                     // coarse buckets (dst >> 8)
#define NN2 (NBUCK * 256)             // 100096: padded node space
#define CBLK 250                      // coarse blocks
#define EPB 6400                      // edges per coarse block (250*6400 = 1.6M)
#define W_SCALE (1.0f / 32767.0f)

__device__ __forceinline__ float lane_bcast(float v, int l) {
    return __uint_as_float(__builtin_amdgcn_readlane(__float_as_uint(v), l));
}
__device__ __forceinline__ float bfu(unsigned short u) {            // bf16 -> f32
    return __uint_as_float(((unsigned)u) << 16);
}
__device__ __forceinline__ unsigned short f2bf(float x) {           // f32 -> bf16 RTN
    unsigned u = __float_as_uint(x);
    return (unsigned short)((u + 0x7FFFu + ((u >> 16) & 1u)) >> 16);
}

// ---------------------------------------------------------------------------
// Phase A1: per-block coarse-bucket histogram (LDS) -> bmat[b][blk]
__global__ __launch_bounds__(256) void k_bhist(const int* __restrict__ dst, int* __restrict__ bmat) {
    __shared__ int bh[NBUCK];
    int t = threadIdx.x, blk = blockIdx.x;
    for (int b = t; b < NBUCK; b += 256) bh[b] = 0;
    __syncthreads();
    int base = blk * EPB;
    for (int r = 0; r < EPB / 256; ++r)
        atomicAdd(&bh[dst[base + r * 256 + t] >> 8], 1);
    __syncthreads();
    for (int b = t; b < NBUCK; b += 256) bmat[b * 256 + blk] = bh[b];
}

// Phase A2: per-bucket exclusive scan over the 250 block counts (column scan)
__global__ __launch_bounds__(256) void k_colscan(int* __restrict__ bmat, int* __restrict__ btotal) {
    __shared__ int s[256];
    int b = blockIdx.x, t = threadIdx.x;
    int v = (t < CBLK) ? bmat[b * 256 + t] : 0;
    s[t] = v;
    __syncthreads();
    for (int off = 1; off < 256; off <<= 1) {
        int x = (t >= off) ? s[t - off] : 0;
        __syncthreads();
        s[t] += x;
        __syncthreads();
    }
    if (t < CBLK) bmat[b * 256 + t] = s[t] - v;   // exclusive within column
    if (t == 255) btotal[b] = s[255];
}

// Generic 391-length exclusive scan in one block (used for cbase and boff)
__global__ __launch_bounds__(512) void k_scan_bsum(const int* __restrict__ in, int* __restrict__ outp) {
    __shared__ int s[512];
    int t = threadIdx.x;
    int v = (t < NB1) ? in[t] : 0;
    s[t] = v;
    __syncthreads();
    for (int off = 1; off < 512; off <<= 1) {
        int x = (t >= off) ? s[t - off] : 0;
        __syncthreads();
        s[t] += x;
        __syncthreads();
    }
    if (t < NB1) outp[t] = s[t] - v;   // exclusive
}

// Phase A3: coarse scatter. Each (block,bucket) owns an exclusive contiguous
// run in C -> writes are short contiguous runs (L2 merges within one XCD).
__global__ __launch_bounds__(256) void k_coarse(
    const int* __restrict__ src, const int* __restrict__ dst, const float* __restrict__ w,
    const int* __restrict__ bmat, const int* __restrict__ cbase, uint2* __restrict__ C)
{
    __shared__ int cur[NBUCK];
    int t = threadIdx.x, blk = blockIdx.x;
    for (int b = t; b < NBUCK; b += 256) cur[b] = cbase[b] + bmat[b * 256 + blk];
    __syncthreads();
    int base = blk * EPB;
    for (int r = 0; r < EPB / 256; ++r) {
        int e = base + r * 256 + t;
        int d = dst[e];
        int q = __float2int_rn(w[e] * 32767.0f);
        unsigned pe = ((unsigned)src[e] << 15) | (unsigned)q;
        int pos = atomicAdd(&cur[d >> 8], 1);
        C[pos] = make_uint2(pe, (unsigned)(d & 255));
    }
}

// Phase B1: per-node counts within each bucket (coalesced region read)
__global__ __launch_bounds__(256) void k_fhist(const uint2* __restrict__ C, const int* __restrict__ cbase,
                                               const int* __restrict__ btotal, int* __restrict__ pcnt) {
    __shared__ int c[256];
    int b = blockIdx.x, t = threadIdx.x;
    c[t] = 0;
    __syncthreads();
    int j0 = cbase[b], j1 = j0 + btotal[b];
    for (int j = j0 + t; j < j1; j += 256) atomicAdd(&c[C[j].y], 1);
    __syncthreads();
    pcnt[b * 256 + t] = c[t];
}

// Phase B2a: per-block sums of PADDED counts (rows padded to multiple of 4)
__global__ __launch_bounds__(SCAN_B) void k_partial(const int* __restrict__ pcnt, int* __restrict__ bsum) {
    __shared__ int s[SCAN_B];
    int b = blockIdx.x, t = threadIdx.x;
    s[t] = (pcnt[b * SCAN_B + t] + 3) & ~3;
    __syncthreads();
    for (int off = SCAN_B / 2; off > 0; off >>= 1) {
        if (t < off) s[t] += s[t + off];
        __syncthreads();
    }
    if (t == 0) bsum[b] = s[0];
}

// Phase B2b: per-block exclusive scan of padded counts -> row_ptr
__global__ __launch_bounds__(SCAN_B) void k_scan_final(const int* __restrict__ pcnt, const int* __restrict__ boff,
                                                       int* __restrict__ row_ptr) {
    __shared__ int s[SCAN_B];
    int b = blockIdx.x, t = threadIdx.x;
    int i = b * SCAN_B + t;
    int v = (pcnt[i] + 3) & ~3;
    s[t] = v;
    __syncthreads();
    for (int off = 1; off < SCAN_B; off <<= 1) {
        int x = (t >= off) ? s[t - off] : 0;
        __syncthreads();
        s[t] += x;
        __syncthreads();
    }
    row_ptr[i] = boff[b] + s[t] - v;
    if (i == NN2 - 1) row_ptr[NN2] = boff[b] + s[t];   // padded total
}

// Phase B3: fine scatter. One block per bucket -> E region has a SINGLE
// writer block (one CU / one L2) -> lines merge fully, WRITE ~= payload.
__global__ __launch_bounds__(256) void k_fine(const uint2* __restrict__ C, const int* __restrict__ cbase,
                                              const int* __restrict__ btotal, const int* __restrict__ row_ptr,
                                              unsigned* __restrict__ E) {
    __shared__ int cur[256];
    int b = blockIdx.x, t = threadIdx.x;
    cur[t] = row_ptr[b * 256 + t];
    __syncthreads();
    int j0 = cbase[b], j1 = j0 + btotal[b];
    for (int j = j0 + t; j < j1; j += 256) {
        uint2 c = C[j];
        int pos = atomicAdd(&cur[c.y], 1);
        E[pos] = c.x;
    }
}

// ---------------------------------------------------------------------------
// Layer 1 (C=1) aggregation + pair pack: p[i] = (agg1[i], x[i])
__global__ __launch_bounds__(256) void k_agg1_pair(const int* __restrict__ rp, const unsigned* __restrict__ E,
                                                   const float* __restrict__ x, float2* __restrict__ p) {
    int i = blockIdx.x * 256 + threadIdx.x;
    if (i >= N_NODES) return;
    int j1 = rp[i + 1];
    float acc = 0.0f;
    for (int j = rp[i]; j < j1; ++j) {
        unsigned e = E[j];
        acc = fmaf((float)(e & 32767u) * W_SCALE, x[e >> 15], acc);
    }
    p[i] = make_float2(acc, x[i]);
}

// ---------------------------------------------------------------------------
// Layer-2 aggregation: gather 8B pairs (L2-resident), reconstruct h1[s][c]
// in-lane. One wave per node, lane = channel. 4 edges per int4 broadcast load.
__global__ __launch_bounds__(256) void k_gather_pair(
    const int* __restrict__ rp, const unsigned* __restrict__ E,
    const float2* __restrict__ p,
    const float* __restrict__ Wr1, const float* __restrict__ b1,
    const float* __restrict__ Wo1, float* __restrict__ agg)
{
    int t = blockIdx.x * 256 + threadIdx.x;
    int node = t >> 6, c = t & 63;
    if (node >= N_NODES) return;
    float wr = Wr1[c], bb = b1[c], wo = Wo1[c];
    int j0 = rp[node], j1 = rp[node + 1];
    const uint4* E4 = (const uint4*)E;
    float acc = 0.0f;
    for (int j4 = (j0 >> 2); j4 < (j1 >> 2); ++j4) {
        uint4 e = E4[j4];
        float2 p0 = p[e.x >> 15];
        float2 p1 = p[e.y >> 15];
        float2 p2 = p[e.z >> 15];
        float2 p3 = p[e.w >> 15];
        float w0 = (float)(e.x & 32767u) * W_SCALE;
        float w1 = (float)(e.y & 32767u) * W_SCALE;
        float w2 = (float)(e.z & 32767u) * W_SCALE;
        float w3 = (float)(e.w & 32767u) * W_SCALE;
        acc = fmaf(w0, fmaxf(fmaf(p0.x, wr, fmaf(p0.y, wo, bb)), 0.0f), acc);
        acc = fmaf(w1, fmaxf(fmaf(p1.x, wr, fmaf(p1.y, wo, bb)), 0.0f), acc);
        acc = fmaf(w2, fmaxf(fmaf(p2.x, wr, fmaf(p2.y, wo, bb)), 0.0f), acc);
        acc = fmaf(w3, fmaxf(fmaf(p3.x, wr, fmaf(p3.y, wo, bb)), 0.0f), acc);
    }
    agg[node * 64 + c] = acc;
}

// ---------------------------------------------------------------------------
// Layer-3 aggregation, grouped: 16 lanes per row, lane group g = lane>>4 owns
// edge j+g; each lane loads ushort4 (4 bf16 channels, 8B) -> one load instr
// fetches 4 edges' rows. 2-deep E prefetch. Butterfly reduce + float4 store.
__global__ __launch_bounds__(256) void k_gather_bf16(
    const int* __restrict__ rp, const unsigned* __restrict__ E,
    const unsigned short* __restrict__ h2, float* __restrict__ agg)
{
    int t = blockIdx.x * 256 + threadIdx.x;
    int node = t >> 6;
    int l = t & 63;
    int g = l >> 4, q = l & 15;
    if (node >= N_NODES) return;
    int j0 = rp[node], j1 = rp[node + 1];
    float4 acc = make_float4(0.0f, 0.0f, 0.0f, 0.0f);
    int j = j0;
    unsigned ec = (j < j1) ? E[j + g] : 0u;
    while (j < j1) {
        int jn = j + 4;
        unsigned src = ec >> 15;
        float wq = (float)(ec & 32767u) * W_SCALE;
        ushort4 rv = *((const ushort4*)(h2 + src * 64) + q);
        unsigned en = (jn < j1) ? E[jn + g] : 0u;
        acc.x = fmaf(wq, bfu(rv.x), acc.x);
        acc.y = fmaf(wq, bfu(rv.y), acc.y);
        acc.z = fmaf(wq, bfu(rv.z), acc.z);
        acc.w = fmaf(wq, bfu(rv.w), acc.w);
        ec = en; j = jn;
    }
    acc.x += __shfl_xor(acc.x, 16); acc.y += __shfl_xor(acc.y, 16);
    acc.z += __shfl_xor(acc.z, 16); acc.w += __shfl_xor(acc.w, 16);
    acc.x += __shfl_xor(acc.x, 32); acc.y += __shfl_xor(acc.y, 32);
    acc.z += __shfl_xor(acc.z, 32); acc.w += __shfl_xor(acc.w, 32);
    if (l < 16) ((float4*)(agg + node * 64))[q] = acc;
}

// ---------------------------------------------------------------------------
// Transform 2: h2 = relu(agg2 @ Wrel2^T + b2 + h1 @ Wroot2^T), h1 recomputed
// from pair p. Weights register-resident per lane; cross-lane via v_readlane.
__global__ __launch_bounds__(256) void k_transform2(
    const float* __restrict__ agg, const float2* __restrict__ p,
    const float* __restrict__ Wrel, const float* __restrict__ brel,
    const float* __restrict__ Wroot,
    const float* __restrict__ Wr1, const float* __restrict__ b1,
    const float* __restrict__ Wo1,
    unsigned short* __restrict__ h2)
{
    int t = threadIdx.x;
    int wv = t >> 6, c = t & 63;
    float rR[64], rO[64];
    #pragma unroll
    for (int q = 0; q < 16; ++q) {
        float4 a = ((const float4*)(Wrel + c * 64))[q];
        rR[4 * q + 0] = a.x; rR[4 * q + 1] = a.y; rR[4 * q + 2] = a.z; rR[4 * q + 3] = a.w;
        float4 b = ((const float4*)(Wroot + c * 64))[q];
        rO[4 * q + 0] = b.x; rO[4 * q + 1] = b.y; rO[4 * q + 2] = b.z; rO[4 * q + 3] = b.w;
    }
    float bc = brel[c];
    float wr1 = Wr1[c], bb1 = b1[c], wo1 = Wo1[c];
    int gw = blockIdx.x * 4 + wv;
    int nw = gridDim.x * 4;
    for (int i = gw; i < N_NODES; i += nw) {
        float av = agg[i * 64 + c];
        float2 pv = p[i];
        float hv = fmaxf(fmaf(pv.x, wr1, fmaf(pv.y, wo1, bb1)), 0.0f);
        float acc = bc;
        #pragma unroll
        for (int k = 0; k < 64; ++k) {
            acc = fmaf(lane_bcast(av, k), rR[k], acc);
            acc = fmaf(lane_bcast(hv, k), rO[k], acc);
        }
        acc = fmaxf(acc, 0.0f);
        h2[i * 64 + c] = f2bf(acc);
    }
}

// Transform 3 + fused mean-pool stage 1: h3 = agg3 @ Wrel3^T + b3 + h2 @ Wroot3^T
// (no relu). h3 never touches memory: each wave owns a CONTIGUOUS node chunk
// (batch is sorted), keeps a per-lane running sum, and flushes one wave-wide
// atomicAdd per graph boundary into sums[g][64] (16 KB, L2-resident).
__global__ __launch_bounds__(256) void k_transform3_pool(
    const float* __restrict__ agg, const unsigned short* __restrict__ h2,
    const float* __restrict__ Wrel, const float* __restrict__ brel,
    const float* __restrict__ Wroot, const int* __restrict__ batch,
    float* __restrict__ sums)
{
    int t = threadIdx.x;
    int wv = t >> 6, c = t & 63;
    float rR[64], rO[64];
    #pragma unroll
    for (int q = 0; q < 16; ++q) {
        float4 a = ((const float4*)(Wrel + c * 64))[q];
        rR[4 * q + 0] = a.x; rR[4 * q + 1] = a.y; rR[4 * q + 2] = a.z; rR[4 * q + 3] = a.w;
        float4 b = ((const float4*)(Wroot + c * 64))[q];
        rO[4 * q + 0] = b.x; rO[4 * q + 1] = b.y; rO[4 * q + 2] = b.z; rO[4 * q + 3] = b.w;
    }
    float bc = brel[c];
    int nwaves = gridDim.x * 4;
    int w = blockIdx.x * 4 + wv;
    int L = (N_NODES + nwaves - 1) / nwaves;
    int i0 = w * L, i1 = min(i0 + L, N_NODES);
    if (i0 >= i1) return;
    float accp = 0.0f;
    int gcur = batch[i0];
    for (int i = i0; i < i1; ++i) {
        float av = agg[i * 64 + c];
        float hv = bfu(h2[i * 64 + c]);
        float acc = bc;
        #pragma unroll
        for (int k = 0; k < 64; ++k) {
            acc = fmaf(lane_bcast(av, k), rR[k], acc);
            acc = fmaf(lane_bcast(hv, k), rO[k], acc);
        }
        int g = batch[i];                       // wave-uniform
        if (g != gcur) {
            atomicAdd(&sums[gcur * 64 + c], accp);
            accp = 0.0f;
            gcur = g;
        }
        accp += acc;
    }
    atomicAdd(&sums[gcur * 64 + c], accp);
}

// Pool stage 2: pooled = sums/count; out = pooled @ Wlin^T + blin. One wave/graph.
__global__ __launch_bounds__(64) void k_pool2(
    const float* __restrict__ sums, const int* __restrict__ batch,
    const float* __restrict__ Wlin, const float* __restrict__ blin,
    float* __restrict__ out)
{
    int g = blockIdx.x;
    int c = threadIdx.x;
    int lo = 0, hi = N_NODES;
    while (lo < hi) { int mid = (lo + hi) >> 1; if (batch[mid] < g) lo = mid + 1; else hi = mid; }
    int s0 = lo;
    lo = 0; hi = N_NODES;
    while (lo < hi) { int mid = (lo + hi) >> 1; if (batch[mid] < g + 1) lo = mid + 1; else hi = mid; }
    int s1 = lo;
    __shared__ float pooled[64];
    float cnt = (float)(s1 - s0);
    pooled[c] = sums[g * 64 + c] / fmaxf(cnt, 1.0f);
    __syncthreads();
    if (c < OUT_CH) {
        float acc = blin[c];
        #pragma unroll 8
        for (int k = 0; k < HIDDEN; ++k) acc += pooled[k] * Wlin[c * 64 + k];
        out[g * OUT_CH + c] = acc;
    }
}

// ---------------------------------------------------------------------------
extern "C" void kernel_launch(void* const* d_in, const int* in_sizes, int n_in,
                              void* d_out, int out_size, void* d_ws, size_t ws_size,
                              hipStream_t stream)
{
    const float* x    = (const float*)d_in[0];
    const int*   ei   = (const int*)d_in[1];      // [2, E]: row0=src, row1=dst
    const int*   src  = ei;
    const int*   dst  = ei + N_EDGES;
    const float* ew   = (const float*)d_in[2];
    const int*   batch= (const int*)d_in[3];
    const float* Wr1  = (const float*)d_in[4];
    const float* b1   = (const float*)d_in[5];
    const float* Wo1  = (const float*)d_in[6];
    const float* Wr2  = (const float*)d_in[7];
    const float* b2   = (const float*)d_in[8];
    const float* Wo2  = (const float*)d_in[9];
    const float* Wr3  = (const float*)d_in[10];
    const float* b3   = (const float*)d_in[11];
    const float* Wo3  = (const float*)d_in[12];
    const float* Wlin = (const float*)d_in[13];
    const float* blin = (const float*)d_in[14];
    float* out = (float*)d_out;

    // workspace layout (~61 MB; 78.6 MB proven safe in round 0)
    char* ws = (char*)d_ws;
    const size_t K = 1024;
    int*            row_ptr = (int*)(ws + 0);               // 404 KB (NN2+1 ints)
    int*            bmat    = (int*)(ws + 512 * K);         // 391*256*4 = 400 KB
    int*            btotal  = (int*)(ws + 1024 * K);        // 1.6 KB
    int*            cbase   = (int*)(ws + 1028 * K);        // 1.6 KB
    int*            bsum    = (int*)(ws + 1032 * K);
    int*            boff    = (int*)(ws + 1036 * K);
    int*            pcnt    = (int*)(ws + 1040 * K);        // 400 KB
    float*          sums    = (float*)(ws + 1444 * K);      // 16 KB pool partials
    float2*         p       = (float2*)(ws + 1536 * K);     // 800 KB
    uint2*          C       = (uint2*)(ws + 2560 * K);      // 12.8 MB
    unsigned*       E       = (unsigned*)(ws + 15360 * K);  // up to 7.6 MB (padded CSR)
    unsigned short* h2      = (unsigned short*)(ws + 23552 * K); // 12.8 MB
    float*          aggbuf  = (float*)(ws + 36864 * K);     // 25.6 MB

    // ---- CSR build: 3-phase counting sort (no global position atomics) ----
    hipMemsetAsync(E, 0, 7800 * K, stream);                       // padding zeros
    hipMemsetAsync(sums, 0, N_GRAPHS * HIDDEN * sizeof(float), stream);
    k_bhist<<<CBLK, 256, 0, stream>>>(dst, bmat);
    k_colscan<<<NBUCK, 256, 0, stream>>>(bmat, btotal);
    k_scan_bsum<<<1, 512, 0, stream>>>(btotal, cbase);
    k_coarse<<<CBLK, 256, 0, stream>>>(src, dst, ew, bmat, cbase, C);
    k_fhist<<<NBUCK, 256, 0, stream>>>(C, cbase, btotal, pcnt);
    k_partial<<<NB1, SCAN_B, 0, stream>>>(pcnt, bsum);
    k_scan_bsum<<<1, 512, 0, stream>>>(bsum, boff);
    k_scan_final<<<NB1, SCAN_B, 0, stream>>>(pcnt, boff, row_ptr);
    k_fine<<<NBUCK, 256, 0, stream>>>(C, cbase, btotal, row_ptr, E);

    // ---- layer 1 (C=1): agg + pack pair (agg1, x) ----
    k_agg1_pair<<<NB1, 256, 0, stream>>>(row_ptr, E, x, p);

    // ---- layer 2: gather from pairs, transform -> h2 (bf16) ----
    k_gather_pair<<<(N_NODES * 64) / 256, 256, 0, stream>>>(row_ptr, E, p, Wr1, b1, Wo1, aggbuf);
    k_transform2<<<1024, 256, 0, stream>>>(aggbuf, p, Wr2, b2, Wo2, Wr1, b1, Wo1, h2);

    // ---- layer 3: gather bf16 rows, transform fused with pool stage 1 ----
    k_gather_bf16<<<(N_NODES * 64) / 256, 256, 0, stream>>>(row_ptr, E, h2, aggbuf);
    k_transform3_pool<<<1024, 256, 0, stream>>>(aggbuf, h2, Wr3, b3, Wo3, batch, sums);

    // ---- pool stage 2: divide + 64->16 linear ----
    k_pool2<<<N_GRAPHS, 64, 0, stream>>>(sums, batch, Wlin, blin, out);
}

// Round 10
// 330.551 us; speedup vs baseline: 9.9050x; 1.2769x over previous
//
#include <hip/hip_runtime.h>

#define N_NODES 100000
#define N_EDGES 1600000
#define HIDDEN 64
#define OUT_CH 16
#define N_GRAPHS 64
#define N_TILES 6250                  // N_NODES / 16
#define SCAN_B 256
#define NB1 391                       // scan blocks; also NBUCK (100096/256)
#define NBUCK 391                     // coarse buckets (dst >> 8)
#define NN2 (NBUCK * 256)             // 100096: padded node space
#define CBLK 250                      // coarse blocks
#define EPB 6400                      // edges per coarse block (250*6400 = 1.6M)
#define W_SCALE (1.0f / 32767.0f)

typedef __attribute__((ext_vector_type(8))) short bf16x8;
typedef __attribute__((ext_vector_type(4))) float f32x4;

__device__ __forceinline__ float bfu(unsigned short u) {            // bf16 -> f32
    return __uint_as_float(((unsigned)u) << 16);
}
__device__ __forceinline__ unsigned short f2bf(float x) {           // f32 -> bf16 RTN
    unsigned u = __float_as_uint(x);
    return (unsigned short)((u + 0x7FFFu + ((u >> 16) & 1u)) >> 16);
}
// load 8 consecutive f32 of W row c starting at k0, convert to bf16x8 frag
__device__ __forceinline__ bf16x8 load_wfrag(const float* __restrict__ W, int c, int k0) {
    float4 a = *(const float4*)(W + c * 64 + k0);
    float4 b = *(const float4*)(W + c * 64 + k0 + 4);
    bf16x8 r;
    r[0] = (short)f2bf(a.x); r[1] = (short)f2bf(a.y); r[2] = (short)f2bf(a.z); r[3] = (short)f2bf(a.w);
    r[4] = (short)f2bf(b.x); r[5] = (short)f2bf(b.y); r[6] = (short)f2bf(b.z); r[7] = (short)f2bf(b.w);
    return r;
}

// ---------------------------------------------------------------------------
// Phase A1: per-block coarse-bucket histogram (LDS) -> bmat[b][blk]
__global__ __launch_bounds__(256) void k_bhist(const int* __restrict__ dst, int* __restrict__ bmat) {
    __shared__ int bh[NBUCK];
    int t = threadIdx.x, blk = blockIdx.x;
    for (int b = t; b < NBUCK; b += 256) bh[b] = 0;
    __syncthreads();
    int base = blk * EPB;
    for (int r = 0; r < EPB / 256; ++r)
        atomicAdd(&bh[dst[base + r * 256 + t] >> 8], 1);
    __syncthreads();
    for (int b = t; b < NBUCK; b += 256) bmat[b * 256 + blk] = bh[b];
}

// Phase A2: per-bucket exclusive scan over the 250 block counts (column scan)
__global__ __launch_bounds__(256) void k_colscan(int* __restrict__ bmat, int* __restrict__ btotal) {
    __shared__ int s[256];
    int b = blockIdx.x, t = threadIdx.x;
    int v = (t < CBLK) ? bmat[b * 256 + t] : 0;
    s[t] = v;
    __syncthreads();
    for (int off = 1; off < 256; off <<= 1) {
        int x = (t >= off) ? s[t - off] : 0;
        __syncthreads();
        s[t] += x;
        __syncthreads();
    }
    if (t < CBLK) bmat[b * 256 + t] = s[t] - v;   // exclusive within column
    if (t == 255) btotal[b] = s[255];
}

// Generic 391-length exclusive scan in one block (used for cbase and boff)
__global__ __launch_bounds__(512) void k_scan_bsum(const int* __restrict__ in, int* __restrict__ outp) {
    __shared__ int s[512];
    int t = threadIdx.x;
    int v = (t < NB1) ? in[t] : 0;
    s[t] = v;
    __syncthreads();
    for (int off = 1; off < 512; off <<= 1) {
        int x = (t >= off) ? s[t - off] : 0;
        __syncthreads();
        s[t] += x;
        __syncthreads();
    }
    if (t < NB1) outp[t] = s[t] - v;   // exclusive
}

// Phase A3: coarse scatter. Each (block,bucket) owns an exclusive contiguous
// run in C -> writes are short contiguous runs (L2 merges within one XCD).
__global__ __launch_bounds__(256) void k_coarse(
    const int* __restrict__ src, const int* __restrict__ dst, const float* __restrict__ w,
    const int* __restrict__ bmat, const int* __restrict__ cbase, uint2* __restrict__ C)
{
    __shared__ int cur[NBUCK];
    int t = threadIdx.x, blk = blockIdx.x;
    for (int b = t; b < NBUCK; b += 256) cur[b] = cbase[b] + bmat[b * 256 + blk];
    __syncthreads();
    int base = blk * EPB;
    for (int r = 0; r < EPB / 256; ++r) {
        int e = base + r * 256 + t;
        int d = dst[e];
        int q = __float2int_rn(w[e] * 32767.0f);
        unsigned pe = ((unsigned)src[e] << 15) | (unsigned)q;
        int pos = atomicAdd(&cur[d >> 8], 1);
        C[pos] = make_uint2(pe, (unsigned)(d & 255));
    }
}

// Phase B1: per-node counts within each bucket (coalesced region read)
__global__ __launch_bounds__(256) void k_fhist(const uint2* __restrict__ C, const int* __restrict__ cbase,
                                               const int* __restrict__ btotal, int* __restrict__ pcnt) {
    __shared__ int c[256];
    int b = blockIdx.x, t = threadIdx.x;
    c[t] = 0;
    __syncthreads();
    int j0 = cbase[b], j1 = j0 + btotal[b];
    for (int j = j0 + t; j < j1; j += 256) atomicAdd(&c[C[j].y], 1);
    __syncthreads();
    pcnt[b * 256 + t] = c[t];
}

// Phase B2a: per-block sums of PADDED counts (rows padded to multiple of 4)
__global__ __launch_bounds__(SCAN_B) void k_partial(const int* __restrict__ pcnt, int* __restrict__ bsum) {
    __shared__ int s[SCAN_B];
    int b = blockIdx.x, t = threadIdx.x;
    s[t] = (pcnt[b * SCAN_B + t] + 3) & ~3;
    __syncthreads();
    for (int off = SCAN_B / 2; off > 0; off >>= 1) {
        if (t < off) s[t] += s[t + off];
        __syncthreads();
    }
    if (t == 0) bsum[b] = s[0];
}

// Phase B2b: per-block exclusive scan of padded counts -> row_ptr
__global__ __launch_bounds__(SCAN_B) void k_scan_final(const int* __restrict__ pcnt, const int* __restrict__ boff,
                                                       int* __restrict__ row_ptr) {
    __shared__ int s[SCAN_B];
    int b = blockIdx.x, t = threadIdx.x;
    int i = b * SCAN_B + t;
    int v = (pcnt[i] + 3) & ~3;
    s[t] = v;
    __syncthreads();
    for (int off = 1; off < SCAN_B; off <<= 1) {
        int x = (t >= off) ? s[t - off] : 0;
        __syncthreads();
        s[t] += x;
        __syncthreads();
    }
    row_ptr[i] = boff[b] + s[t] - v;
    if (i == NN2 - 1) row_ptr[NN2] = boff[b] + s[t];   // padded total
}

// Phase B3: fine scatter. One block per bucket -> single writer -> lines merge.
__global__ __launch_bounds__(256) void k_fine(const uint2* __restrict__ C, const int* __restrict__ cbase,
                                              const int* __restrict__ btotal, const int* __restrict__ row_ptr,
                                              unsigned* __restrict__ E) {
    __shared__ int cur[256];
    int b = blockIdx.x, t = threadIdx.x;
    cur[t] = row_ptr[b * 256 + t];
    __syncthreads();
    int j0 = cbase[b], j1 = j0 + btotal[b];
    for (int j = j0 + t; j < j1; j += 256) {
        uint2 c = C[j];
        int pos = atomicAdd(&cur[c.y], 1);
        E[pos] = c.x;
    }
}

// ---------------------------------------------------------------------------
// Layer 1 (C=1) aggregation + pair pack: p[i] = (agg1[i], x[i])
__global__ __launch_bounds__(256) void k_agg1_pair(const int* __restrict__ rp, const unsigned* __restrict__ E,
                                                   const float* __restrict__ x, float2* __restrict__ p) {
    int i = blockIdx.x * 256 + threadIdx.x;
    if (i >= N_NODES) return;
    int j1 = rp[i + 1];
    float acc = 0.0f;
    for (int j = rp[i]; j < j1; ++j) {
        unsigned e = E[j];
        acc = fmaf((float)(e & 32767u) * W_SCALE, x[e >> 15], acc);
    }
    p[i] = make_float2(acc, x[i]);
}

// ---------------------------------------------------------------------------
// Layer-2 aggregation: gather 8B pairs (L2-resident), reconstruct h1[s][c]
// in-lane. One wave per node, lane = channel. Output agg in bf16.
__global__ __launch_bounds__(256) void k_gather_pair(
    const int* __restrict__ rp, const unsigned* __restrict__ E,
    const float2* __restrict__ p,
    const float* __restrict__ Wr1, const float* __restrict__ b1,
    const float* __restrict__ Wo1, unsigned short* __restrict__ agg)
{
    int t = blockIdx.x * 256 + threadIdx.x;
    int node = t >> 6, c = t & 63;
    if (node >= N_NODES) return;
    float wr = Wr1[c], bb = b1[c], wo = Wo1[c];
    int j0 = rp[node], j1 = rp[node + 1];
    const uint4* E4 = (const uint4*)E;
    float acc = 0.0f;
    for (int j4 = (j0 >> 2); j4 < (j1 >> 2); ++j4) {
        uint4 e = E4[j4];
        float2 p0 = p[e.x >> 15];
        float2 p1 = p[e.y >> 15];
        float2 p2 = p[e.z >> 15];
        float2 p3 = p[e.w >> 15];
        float w0 = (float)(e.x & 32767u) * W_SCALE;
        float w1 = (float)(e.y & 32767u) * W_SCALE;
        float w2 = (float)(e.z & 32767u) * W_SCALE;
        float w3 = (float)(e.w & 32767u) * W_SCALE;
        acc = fmaf(w0, fmaxf(fmaf(p0.x, wr, fmaf(p0.y, wo, bb)), 0.0f), acc);
        acc = fmaf(w1, fmaxf(fmaf(p1.x, wr, fmaf(p1.y, wo, bb)), 0.0f), acc);
        acc = fmaf(w2, fmaxf(fmaf(p2.x, wr, fmaf(p2.y, wo, bb)), 0.0f), acc);
        acc = fmaf(w3, fmaxf(fmaf(p3.x, wr, fmaf(p3.y, wo, bb)), 0.0f), acc);
    }
    agg[node * 64 + c] = f2bf(acc);
}

// ---------------------------------------------------------------------------
// Layer-3 aggregation, grouped: 16 lanes per row, lane group g owns edge j+g;
// ushort4 loads (4 bf16), butterfly reduce, bf16 ushort4 store.
__global__ __launch_bounds__(256) void k_gather_bf16(
    const int* __restrict__ rp, const unsigned* __restrict__ E,
    const unsigned short* __restrict__ h2, unsigned short* __restrict__ agg)
{
    int t = blockIdx.x * 256 + threadIdx.x;
    int node = t >> 6;
    int l = t & 63;
    int g = l >> 4, q = l & 15;
    if (node >= N_NODES) return;
    int j0 = rp[node], j1 = rp[node + 1];
    float4 acc = make_float4(0.0f, 0.0f, 0.0f, 0.0f);
    int j = j0;
    unsigned ec = (j < j1) ? E[j + g] : 0u;
    while (j < j1) {
        int jn = j + 4;
        unsigned src = ec >> 15;
        float wq = (float)(ec & 32767u) * W_SCALE;
        ushort4 rv = *((const ushort4*)(h2 + src * 64) + q);
        unsigned en = (jn < j1) ? E[jn + g] : 0u;
        acc.x = fmaf(wq, bfu(rv.x), acc.x);
        acc.y = fmaf(wq, bfu(rv.y), acc.y);
        acc.z = fmaf(wq, bfu(rv.z), acc.z);
        acc.w = fmaf(wq, bfu(rv.w), acc.w);
        ec = en; j = jn;
    }
    acc.x += __shfl_xor(acc.x, 16); acc.y += __shfl_xor(acc.y, 16);
    acc.z += __shfl_xor(acc.z, 16); acc.w += __shfl_xor(acc.w, 16);
    acc.x += __shfl_xor(acc.x, 32); acc.y += __shfl_xor(acc.y, 32);
    acc.z += __shfl_xor(acc.z, 32); acc.w += __shfl_xor(acc.w, 32);
    if (l < 16) {
        ushort4 st;
        st.x = f2bf(acc.x); st.y = f2bf(acc.y); st.z = f2bf(acc.z); st.w = f2bf(acc.w);
        ((ushort4*)(agg + node * 64))[q] = st;
    }
}

// ---------------------------------------------------------------------------
// MFMA transform 2: h2 = relu(agg2 @ Wrel2^T + b2 + h1 @ Wroot2^T), h1
// recomputed from pair p in bf16. Per 16-node tile: A = weight rows
// (m=lane&15 -> c, k=(lane>>4)*8+j), B = node rows (n=lane&15 -> node),
// D: col=lane&15=node, row=(lane>>4)*4+j=c (m89-verified layout).
__global__ __launch_bounds__(256) void k_transform2_mfma(
    const unsigned short* __restrict__ agg, const float2* __restrict__ p,
    const float* __restrict__ Wrel, const float* __restrict__ brel,
    const float* __restrict__ Wroot,
    const float* __restrict__ Wr1, const float* __restrict__ b1,
    const float* __restrict__ Wo1,
    unsigned short* __restrict__ h2)
{
    int t = threadIdx.x;
    int wv = t >> 6, l = t & 63;
    int lo = l & 15, hi = l >> 4;
    bf16x8 wR[4][2], wO[4][2];
    #pragma unroll
    for (int ct = 0; ct < 4; ++ct)
        #pragma unroll
        for (int kh = 0; kh < 2; ++kh) {
            wR[ct][kh] = load_wfrag(Wrel,  ct * 16 + lo, kh * 32 + hi * 8);
            wO[ct][kh] = load_wfrag(Wroot, ct * 16 + lo, kh * 32 + hi * 8);
        }
    float bias[4][4];
    #pragma unroll
    for (int ct = 0; ct < 4; ++ct)
        #pragma unroll
        for (int j = 0; j < 4; ++j) bias[ct][j] = brel[ct * 16 + hi * 4 + j];
    float w1a[16], w1b[16], w1c[16];           // [kh*8+j] at k = kh*32+hi*8+j
    #pragma unroll
    for (int kh = 0; kh < 2; ++kh)
        #pragma unroll
        for (int j = 0; j < 8; ++j) {
            int idx = kh * 32 + hi * 8 + j;
            w1a[kh * 8 + j] = Wr1[idx]; w1b[kh * 8 + j] = Wo1[idx]; w1c[kh * 8 + j] = b1[idx];
        }
    int wid = blockIdx.x * 4 + wv, nw = gridDim.x * 4;
    for (int tile = wid; tile < N_TILES; tile += nw) {
        int i = tile * 16 + lo;
        float2 pv = p[i];
        bf16x8 bA0 = *(const bf16x8*)(agg + i * 64 + hi * 8);
        bf16x8 bA1 = *(const bf16x8*)(agg + i * 64 + 32 + hi * 8);
        bf16x8 bH0, bH1;
        #pragma unroll
        for (int j = 0; j < 8; ++j) {
            float h0 = fmaxf(fmaf(pv.x, w1a[j],     fmaf(pv.y, w1b[j],     w1c[j])),     0.0f);
            float h1 = fmaxf(fmaf(pv.x, w1a[8 + j], fmaf(pv.y, w1b[8 + j], w1c[8 + j])), 0.0f);
            bH0[j] = (short)f2bf(h0);
            bH1[j] = (short)f2bf(h1);
        }
        #pragma unroll
        for (int ct = 0; ct < 4; ++ct) {
            f32x4 acc = {bias[ct][0], bias[ct][1], bias[ct][2], bias[ct][3]};
            acc = __builtin_amdgcn_mfma_f32_16x16x32_bf16(wR[ct][0], bA0, acc, 0, 0, 0);
            acc = __builtin_amdgcn_mfma_f32_16x16x32_bf16(wR[ct][1], bA1, acc, 0, 0, 0);
            acc = __builtin_amdgcn_mfma_f32_16x16x32_bf16(wO[ct][0], bH0, acc, 0, 0, 0);
            acc = __builtin_amdgcn_mfma_f32_16x16x32_bf16(wO[ct][1], bH1, acc, 0, 0, 0);
            ushort4 st;
            st.x = f2bf(fmaxf(acc[0], 0.0f)); st.y = f2bf(fmaxf(acc[1], 0.0f));
            st.z = f2bf(fmaxf(acc[2], 0.0f)); st.w = f2bf(fmaxf(acc[3], 0.0f));
            *(ushort4*)(h2 + i * 64 + ct * 16 + hi * 4) = st;
        }
    }
}

// Butterfly-reduce pool over the 16 node-lanes; lanes lo==0 flush to sums.
__device__ __forceinline__ void flush_pool(float* pool, int gcur, float* __restrict__ sums,
                                           int lo, int hi) {
    #pragma unroll
    for (int n = 0; n < 16; ++n) {
        float v = pool[n];
        v += __shfl_xor(v, 1); v += __shfl_xor(v, 2);
        v += __shfl_xor(v, 4); v += __shfl_xor(v, 8);
        if (lo == 0) atomicAdd(&sums[gcur * 64 + (n >> 2) * 16 + hi * 4 + (n & 3)], v);
        pool[n] = 0.0f;
    }
}

// MFMA transform 3 + fused mean-pool stage 1 (no relu; h3 never hits memory).
// Contiguous tile chunks per wave; pool in registers, flush at graph
// boundaries / wave end; rare intra-tile-boundary tiles take per-lane atomics.
__global__ __launch_bounds__(256) void k_transform3_pool_mfma(
    const unsigned short* __restrict__ agg, const unsigned short* __restrict__ h2,
    const float* __restrict__ Wrel, const float* __restrict__ brel,
    const float* __restrict__ Wroot, const int* __restrict__ batch,
    float* __restrict__ sums)
{
    int t = threadIdx.x;
    int wv = t >> 6, l = t & 63;
    int lo = l & 15, hi = l >> 4;
    bf16x8 wR[4][2], wO[4][2];
    #pragma unroll
    for (int ct = 0; ct < 4; ++ct)
        #pragma unroll
        for (int kh = 0; kh < 2; ++kh) {
            wR[ct][kh] = load_wfrag(Wrel,  ct * 16 + lo, kh * 32 + hi * 8);
            wO[ct][kh] = load_wfrag(Wroot, ct * 16 + lo, kh * 32 + hi * 8);
        }
    float bias[4][4];
    #pragma unroll
    for (int ct = 0; ct < 4; ++ct)
        #pragma unroll
        for (int j = 0; j < 4; ++j) bias[ct][j] = brel[ct * 16 + hi * 4 + j];

    int nw = gridDim.x * 4;
    int wid = blockIdx.x * 4 + wv;
    int tpw = (N_TILES + nw - 1) / nw;
    int t0 = wid * tpw, t1 = min(t0 + tpw, N_TILES);
    if (t0 >= t1) return;

    float pool[16];
    #pragma unroll
    for (int n = 0; n < 16; ++n) pool[n] = 0.0f;
    int gcur = batch[t0 * 16];

    for (int tile = t0; tile < t1; ++tile) {
        int i = tile * 16 + lo;
        int gi = batch[i];
        bf16x8 bA0 = *(const bf16x8*)(agg + i * 64 + hi * 8);
        bf16x8 bA1 = *(const bf16x8*)(agg + i * 64 + 32 + hi * 8);
        bf16x8 bH0 = *(const bf16x8*)(h2  + i * 64 + hi * 8);
        bf16x8 bH1 = *(const bf16x8*)(h2  + i * 64 + 32 + hi * 8);
        f32x4 acc[4];
        #pragma unroll
        for (int ct = 0; ct < 4; ++ct) {
            f32x4 a = {bias[ct][0], bias[ct][1], bias[ct][2], bias[ct][3]};
            a = __builtin_amdgcn_mfma_f32_16x16x32_bf16(wR[ct][0], bA0, a, 0, 0, 0);
            a = __builtin_amdgcn_mfma_f32_16x16x32_bf16(wR[ct][1], bA1, a, 0, 0, 0);
            a = __builtin_amdgcn_mfma_f32_16x16x32_bf16(wO[ct][0], bH0, a, 0, 0, 0);
            a = __builtin_amdgcn_mfma_f32_16x16x32_bf16(wO[ct][1], bH1, a, 0, 0, 0);
            acc[ct] = a;
        }
        int gfirst = __shfl(gi, 0);
        int glast  = __shfl(gi, 15);
        if (gfirst != glast) {
            // graph boundary inside tile: flush, then per-lane atomics
            flush_pool(pool, gcur, sums, lo, hi);
            #pragma unroll
            for (int ct = 0; ct < 4; ++ct)
                #pragma unroll
                for (int j = 0; j < 4; ++j)
                    atomicAdd(&sums[gi * 64 + ct * 16 + hi * 4 + j], acc[ct][j]);
            gcur = glast;
        } else {
            if (gfirst != gcur) {
                flush_pool(pool, gcur, sums, lo, hi);
                gcur = gfirst;
            }
            #pragma unroll
            for (int ct = 0; ct < 4; ++ct)
                #pragma unroll
                for (int j = 0; j < 4; ++j) pool[ct * 4 + j] += acc[ct][j];
        }
    }
    flush_pool(pool, gcur, sums, lo, hi);
}

// Pool stage 2: pooled = sums/count; out = pooled @ Wlin^T + blin. One wave/graph.
__global__ __launch_bounds__(64) void k_pool2(
    const float* __restrict__ sums, const int* __restrict__ batch,
    const float* __restrict__ Wlin, const float* __restrict__ blin,
    float* __restrict__ out)
{
    int g = blockIdx.x;
    int c = threadIdx.x;
    int lo = 0, hi = N_NODES;
    while (lo < hi) { int mid = (lo + hi) >> 1; if (batch[mid] < g) lo = mid + 1; else hi = mid; }
    int s0 = lo;
    lo = 0; hi = N_NODES;
    while (lo < hi) { int mid = (lo + hi) >> 1; if (batch[mid] < g + 1) lo = mid + 1; else hi = mid; }
    int s1 = lo;
    __shared__ float pooled[64];
    float cnt = (float)(s1 - s0);
    pooled[c] = sums[g * 64 + c] / fmaxf(cnt, 1.0f);
    __syncthreads();
    if (c < OUT_CH) {
        float acc = blin[c];
        #pragma unroll 8
        for (int k = 0; k < HIDDEN; ++k) acc += pooled[k] * Wlin[c * 64 + k];
        out[g * OUT_CH + c] = acc;
    }
}

// ---------------------------------------------------------------------------
extern "C" void kernel_launch(void* const* d_in, const int* in_sizes, int n_in,
                              void* d_out, int out_size, void* d_ws, size_t ws_size,
                              hipStream_t stream)
{
    const float* x    = (const float*)d_in[0];
    const int*   ei   = (const int*)d_in[1];      // [2, E]: row0=src, row1=dst
    const int*   src  = ei;
    const int*   dst  = ei + N_EDGES;
    const float* ew   = (const float*)d_in[2];
    const int*   batch= (const int*)d_in[3];
    const float* Wr1  = (const float*)d_in[4];
    const float* b1   = (const float*)d_in[5];
    const float* Wo1  = (const float*)d_in[6];
    const float* Wr2  = (const float*)d_in[7];
    const float* b2   = (const float*)d_in[8];
    const float* Wo2  = (const float*)d_in[9];
    const float* Wr3  = (const float*)d_in[10];
    const float* b3   = (const float*)d_in[11];
    const float* Wo3  = (const float*)d_in[12];
    const float* Wlin = (const float*)d_in[13];
    const float* blin = (const float*)d_in[14];
    float* out = (float*)d_out;

    // workspace layout (~50 MB; 78.6 MB proven safe in round 0)
    char* ws = (char*)d_ws;
    const size_t K = 1024;
    int*            row_ptr = (int*)(ws + 0);               // 404 KB (NN2+1 ints)
    int*            bmat    = (int*)(ws + 512 * K);         // 391*256*4 = 400 KB
    int*            btotal  = (int*)(ws + 1024 * K);        // 1.6 KB
    int*            cbase   = (int*)(ws + 1028 * K);        // 1.6 KB
    int*            bsum    = (int*)(ws + 1032 * K);
    int*            boff    = (int*)(ws + 1036 * K);
    int*            pcnt    = (int*)(ws + 1040 * K);        // 400 KB
    float*          sums    = (float*)(ws + 1444 * K);      // 16 KB pool partials
    float2*         p       = (float2*)(ws + 1536 * K);     // 800 KB
    uint2*          C       = (uint2*)(ws + 2560 * K);      // 12.8 MB
    unsigned*       E       = (unsigned*)(ws + 15360 * K);  // up to 7.6 MB (padded CSR)
    unsigned short* h2      = (unsigned short*)(ws + 23552 * K); // 12.8 MB
    unsigned short* aggbuf  = (unsigned short*)(ws + 36864 * K); // 12.8 MB (bf16)

    // ---- CSR build: 3-phase counting sort (no global position atomics) ----
    hipMemsetAsync(E, 0, 7800 * K, stream);                       // padding zeros
    hipMemsetAsync(sums, 0, N_GRAPHS * HIDDEN * sizeof(float), stream);
    k_bhist<<<CBLK, 256, 0, stream>>>(dst, bmat);
    k_colscan<<<NBUCK, 256, 0, stream>>>(bmat, btotal);
    k_scan_bsum<<<1, 512, 0, stream>>>(btotal, cbase);
    k_coarse<<<CBLK, 256, 0, stream>>>(src, dst, ew, bmat, cbase, C);
    k_fhist<<<NBUCK, 256, 0, stream>>>(C, cbase, btotal, pcnt);
    k_partial<<<NB1, SCAN_B, 0, stream>>>(pcnt, bsum);
    k_scan_bsum<<<1, 512, 0, stream>>>(bsum, boff);
    k_scan_final<<<NB1, SCAN_B, 0, stream>>>(pcnt, boff, row_ptr);
    k_fine<<<NBUCK, 256, 0, stream>>>(C, cbase, btotal, row_ptr, E);

    // ---- layer 1 (C=1): agg + pack pair (agg1, x) ----
    k_agg1_pair<<<NB1, 256, 0, stream>>>(row_ptr, E, x, p);

    // ---- layer 2: gather from pairs (bf16 agg), MFMA transform -> h2 (bf16) ----
    k_gather_pair<<<(N_NODES * 64) / 256, 256, 0, stream>>>(row_ptr, E, p, Wr1, b1, Wo1, aggbuf);
    k_transform2_mfma<<<512, 256, 0, stream>>>(aggbuf, p, Wr2, b2, Wo2, Wr1, b1, Wo1, h2);

    // ---- layer 3: gather bf16 rows, MFMA transform fused with pool stage 1 ----
    k_gather_bf16<<<(N_NODES * 64) / 256, 256, 0, stream>>>(row_ptr, E, h2, aggbuf);
    k_transform3_pool_mfma<<<512, 256, 0, stream>>>(aggbuf, h2, Wr3, b3, Wo3, batch, sums);

    // ---- pool stage 2: divide + 64->16 linear ----
    k_pool2<<<N_GRAPHS, 64, 0, stream>>>(sums, batch, Wlin, blin, out);
}

// Round 11
// 295.728 us; speedup vs baseline: 11.0713x; 1.1178x over previous
//
#include <hip/hip_runtime.h>

#define N_NODES 100000
#define N_EDGES 1600000
#define HIDDEN 64
#define OUT_CH 16
#define N_GRAPHS 64
#define N_TILES 6250                  // N_NODES / 16
#define SCAN_B 256
#define NB1 391                       // scan blocks; also NBUCK (100096/256)
#define NBUCK 391                     // coarse buckets (dst >> 8)
#define NN2 (NBUCK * 256)             // 100096: padded node space
#define CBLK 250                      // coarse blocks
#define EPB 6400                      // edges per coarse block (250*6400 = 1.6M)
#define W_SCALE (1.0f / 32767.0f)

typedef __attribute__((ext_vector_type(8))) short bf16x8;
typedef __attribute__((ext_vector_type(4))) float f32x4;

__device__ __forceinline__ float bfu(unsigned short u) {            // bf16 -> f32
    return __uint_as_float(((unsigned)u) << 16);
}
__device__ __forceinline__ unsigned short f2bf(float x) {           // f32 -> bf16 RTN
    unsigned u = __float_as_uint(x);
    return (unsigned short)((u + 0x7FFFu + ((u >> 16) & 1u)) >> 16);
}
// load 8 consecutive f32 of W row c starting at k0, convert to bf16x8 frag
__device__ __forceinline__ bf16x8 load_wfrag(const float* __restrict__ W, int c, int k0) {
    float4 a = *(const float4*)(W + c * 64 + k0);
    float4 b = *(const float4*)(W + c * 64 + k0 + 4);
    bf16x8 r;
    r[0] = (short)f2bf(a.x); r[1] = (short)f2bf(a.y); r[2] = (short)f2bf(a.z); r[3] = (short)f2bf(a.w);
    r[4] = (short)f2bf(b.x); r[5] = (short)f2bf(b.y); r[6] = (short)f2bf(b.z); r[7] = (short)f2bf(b.w);
    return r;
}

// ---------------------------------------------------------------------------
// Phase A1: per-block coarse-bucket histogram (LDS) -> bmat[b][blk]
__global__ __launch_bounds__(256) void k_bhist(const int* __restrict__ dst, int* __restrict__ bmat) {
    __shared__ int bh[NBUCK];
    int t = threadIdx.x, blk = blockIdx.x;
    for (int b = t; b < NBUCK; b += 256) bh[b] = 0;
    __syncthreads();
    int base = blk * EPB;
    for (int r = 0; r < EPB / 256; ++r)
        atomicAdd(&bh[dst[base + r * 256 + t] >> 8], 1);
    __syncthreads();
    for (int b = t; b < NBUCK; b += 256) bmat[b * 256 + blk] = bh[b];
}

// Phase A2: per-bucket exclusive scan over the 250 block counts (column scan)
__global__ __launch_bounds__(256) void k_colscan(int* __restrict__ bmat, int* __restrict__ btotal) {
    __shared__ int s[256];
    int b = blockIdx.x, t = threadIdx.x;
    int v = (t < CBLK) ? bmat[b * 256 + t] : 0;
    s[t] = v;
    __syncthreads();
    for (int off = 1; off < 256; off <<= 1) {
        int x = (t >= off) ? s[t - off] : 0;
        __syncthreads();
        s[t] += x;
        __syncthreads();
    }
    if (t < CBLK) bmat[b * 256 + t] = s[t] - v;   // exclusive within column
    if (t == 255) btotal[b] = s[255];
}

// Generic 391-length exclusive scan in one block (used for cbase and boff)
__global__ __launch_bounds__(512) void k_scan_bsum(const int* __restrict__ in, int* __restrict__ outp) {
    __shared__ int s[512];
    int t = threadIdx.x;
    int v = (t < NB1) ? in[t] : 0;
    s[t] = v;
    __syncthreads();
    for (int off = 1; off < 512; off <<= 1) {
        int x = (t >= off) ? s[t - off] : 0;
        __syncthreads();
        s[t] += x;
        __syncthreads();
    }
    if (t < NB1) outp[t] = s[t] - v;   // exclusive
}

// Phase A3: coarse scatter. Each (block,bucket) owns an exclusive contiguous
// run in C -> writes are short contiguous runs (L2 merges within one XCD).
__global__ __launch_bounds__(256) void k_coarse(
    const int* __restrict__ src, const int* __restrict__ dst, const float* __restrict__ w,
    const int* __restrict__ bmat, const int* __restrict__ cbase, uint2* __restrict__ C)
{
    __shared__ int cur[NBUCK];
    int t = threadIdx.x, blk = blockIdx.x;
    for (int b = t; b < NBUCK; b += 256) cur[b] = cbase[b] + bmat[b * 256 + blk];
    __syncthreads();
    int base = blk * EPB;
    for (int r = 0; r < EPB / 256; ++r) {
        int e = base + r * 256 + t;
        int d = dst[e];
        int q = __float2int_rn(w[e] * 32767.0f);
        unsigned pe = ((unsigned)src[e] << 15) | (unsigned)q;
        int pos = atomicAdd(&cur[d >> 8], 1);
        C[pos] = make_uint2(pe, (unsigned)(d & 255));
    }
}

// Phase B1: per-node counts within each bucket (coalesced region read)
__global__ __launch_bounds__(256) void k_fhist(const uint2* __restrict__ C, const int* __restrict__ cbase,
                                               const int* __restrict__ btotal, int* __restrict__ pcnt) {
    __shared__ int c[256];
    int b = blockIdx.x, t = threadIdx.x;
    c[t] = 0;
    __syncthreads();
    int j0 = cbase[b], j1 = j0 + btotal[b];
    for (int j = j0 + t; j < j1; j += 256) atomicAdd(&c[C[j].y], 1);
    __syncthreads();
    pcnt[b * 256 + t] = c[t];
}

// Phase B2a: per-block sums of PADDED counts (rows padded to multiple of 4)
__global__ __launch_bounds__(SCAN_B) void k_partial(const int* __restrict__ pcnt, int* __restrict__ bsum) {
    __shared__ int s[SCAN_B];
    int b = blockIdx.x, t = threadIdx.x;
    s[t] = (pcnt[b * SCAN_B + t] + 3) & ~3;
    __syncthreads();
    for (int off = SCAN_B / 2; off > 0; off >>= 1) {
        if (t < off) s[t] += s[t + off];
        __syncthreads();
    }
    if (t == 0) bsum[b] = s[0];
}

// Phase B2b: per-block exclusive scan of padded counts -> row_ptr
__global__ __launch_bounds__(SCAN_B) void k_scan_final(const int* __restrict__ pcnt, const int* __restrict__ boff,
                                                       int* __restrict__ row_ptr) {
    __shared__ int s[SCAN_B];
    int b = blockIdx.x, t = threadIdx.x;
    int i = b * SCAN_B + t;
    int v = (pcnt[i] + 3) & ~3;
    s[t] = v;
    __syncthreads();
    for (int off = 1; off < SCAN_B; off <<= 1) {
        int x = (t >= off) ? s[t - off] : 0;
        __syncthreads();
        s[t] += x;
        __syncthreads();
    }
    row_ptr[i] = boff[b] + s[t] - v;
    if (i == NN2 - 1) row_ptr[NN2] = boff[b] + s[t];   // padded total
}

// Phase B3: fine scatter + FUSED layer-1 aggregation. One block per bucket ->
// single writer -> lines merge. After the barrier (vmcnt drained), the same
// block aggregates its own nodes' rows (L2-hot E) and packs p = (agg1, x).
__global__ __launch_bounds__(256) void k_fine(const uint2* __restrict__ C, const int* __restrict__ cbase,
                                              const int* __restrict__ btotal, const int* __restrict__ row_ptr,
                                              const float* __restrict__ x,
                                              unsigned* __restrict__ E, float2* __restrict__ p) {
    __shared__ int cur[256];
    int b = blockIdx.x, t = threadIdx.x;
    int rp0 = row_ptr[b * 256 + t];
    cur[t] = rp0;
    __syncthreads();
    int j0 = cbase[b], j1 = j0 + btotal[b];
    for (int j = j0 + t; j < j1; j += 256) {
        uint2 c = C[j];
        int pos = atomicAdd(&cur[c.y], 1);
        E[pos] = c.x;
    }
    __syncthreads();
    int i = b * 256 + t;
    if (i < N_NODES) {
        int jend = cur[t];
        float acc = 0.0f;
        for (int j = rp0; j < jend; ++j) {
            unsigned e = E[j];
            acc = fmaf((float)(e & 32767u) * W_SCALE, x[e >> 15], acc);
        }
        p[i] = make_float2(acc, x[i]);
    }
}

// ---------------------------------------------------------------------------
// Layer-2 aggregation, grouped + 2-deep pipelined: 4 lane-groups of 16; group
// g owns edge slot j+g; lane handles channels 4q..4q+3. 8 p-loads in flight,
// dual accumulators. Cross-group butterfly + bf16 ushort4 store.
__global__ __launch_bounds__(256) void k_gather_pair(
    const int* __restrict__ rp, const unsigned* __restrict__ E,
    const float2* __restrict__ p,
    const float* __restrict__ Wr1, const float* __restrict__ b1,
    const float* __restrict__ Wo1, unsigned short* __restrict__ agg)
{
    int t = blockIdx.x * 256 + threadIdx.x;
    int node = t >> 6;
    int l = t & 63;
    int g = l >> 4, q = l & 15;
    if (node >= N_NODES) return;
    float4 wr = *(const float4*)(Wr1 + q * 4);
    float4 wo = *(const float4*)(Wo1 + q * 4);
    float4 bb = *(const float4*)(b1  + q * 4);
    int j0 = rp[node], j1 = rp[node + 1];
    float4 a0 = make_float4(0.f, 0.f, 0.f, 0.f);
    float4 a1 = make_float4(0.f, 0.f, 0.f, 0.f);
    int j = j0;
    // zero entries (src=0, w=0) make all OOB prefetches harmless
    unsigned ec0 = (j     < j1) ? E[j + g]     : 0u;
    unsigned ec1 = (j + 4 < j1) ? E[j + 4 + g] : 0u;
    while (j < j1) {
        float2 p0 = p[ec0 >> 15];
        float2 p1 = p[ec1 >> 15];
        unsigned en0 = (j + 8  < j1) ? E[j + 8 + g]  : 0u;
        unsigned en1 = (j + 12 < j1) ? E[j + 12 + g] : 0u;
        float w0 = (float)(ec0 & 32767u) * W_SCALE;
        float w1 = (float)(ec1 & 32767u) * W_SCALE;
        a0.x = fmaf(w0, fmaxf(fmaf(p0.x, wr.x, fmaf(p0.y, wo.x, bb.x)), 0.0f), a0.x);
        a0.y = fmaf(w0, fmaxf(fmaf(p0.x, wr.y, fmaf(p0.y, wo.y, bb.y)), 0.0f), a0.y);
        a0.z = fmaf(w0, fmaxf(fmaf(p0.x, wr.z, fmaf(p0.y, wo.z, bb.z)), 0.0f), a0.z);
        a0.w = fmaf(w0, fmaxf(fmaf(p0.x, wr.w, fmaf(p0.y, wo.w, bb.w)), 0.0f), a0.w);
        a1.x = fmaf(w1, fmaxf(fmaf(p1.x, wr.x, fmaf(p1.y, wo.x, bb.x)), 0.0f), a1.x);
        a1.y = fmaf(w1, fmaxf(fmaf(p1.x, wr.y, fmaf(p1.y, wo.y, bb.y)), 0.0f), a1.y);
        a1.z = fmaf(w1, fmaxf(fmaf(p1.x, wr.z, fmaf(p1.y, wo.z, bb.z)), 0.0f), a1.z);
        a1.w = fmaf(w1, fmaxf(fmaf(p1.x, wr.w, fmaf(p1.y, wo.w, bb.w)), 0.0f), a1.w);
        ec0 = en0; ec1 = en1; j += 8;
    }
    float4 acc;
    acc.x = a0.x + a1.x; acc.y = a0.y + a1.y; acc.z = a0.z + a1.z; acc.w = a0.w + a1.w;
    acc.x += __shfl_xor(acc.x, 16); acc.y += __shfl_xor(acc.y, 16);
    acc.z += __shfl_xor(acc.z, 16); acc.w += __shfl_xor(acc.w, 16);
    acc.x += __shfl_xor(acc.x, 32); acc.y += __shfl_xor(acc.y, 32);
    acc.z += __shfl_xor(acc.z, 32); acc.w += __shfl_xor(acc.w, 32);
    if (l < 16) {
        ushort4 st;
        st.x = f2bf(acc.x); st.y = f2bf(acc.y); st.z = f2bf(acc.z); st.w = f2bf(acc.w);
        ((ushort4*)(agg + node * 64))[q] = st;
    }
}

// ---------------------------------------------------------------------------
// Layer-3 aggregation, grouped + 2-deep pipelined: group g owns edge slot j+g;
// lane q loads 8B of the 128B row (coalesced per group). 8 row-loads in
// flight, dual accumulators. Butterfly reduce + bf16 ushort4 store.
__global__ __launch_bounds__(256) void k_gather_bf16(
    const int* __restrict__ rp, const unsigned* __restrict__ E,
    const unsigned short* __restrict__ h2, unsigned short* __restrict__ agg)
{
    int t = blockIdx.x * 256 + threadIdx.x;
    int node = t >> 6;
    int l = t & 63;
    int g = l >> 4, q = l & 15;
    if (node >= N_NODES) return;
    int j0 = rp[node], j1 = rp[node + 1];
    float4 a0 = make_float4(0.f, 0.f, 0.f, 0.f);
    float4 a1 = make_float4(0.f, 0.f, 0.f, 0.f);
    int j = j0;
    unsigned ec0 = (j     < j1) ? E[j + g]     : 0u;
    unsigned ec1 = (j + 4 < j1) ? E[j + 4 + g] : 0u;
    while (j < j1) {
        ushort4 r0 = *((const ushort4*)(h2 + (ec0 >> 15) * 64) + q);
        ushort4 r1 = *((const ushort4*)(h2 + (ec1 >> 15) * 64) + q);
        unsigned en0 = (j + 8  < j1) ? E[j + 8 + g]  : 0u;
        unsigned en1 = (j + 12 < j1) ? E[j + 12 + g] : 0u;
        float w0 = (float)(ec0 & 32767u) * W_SCALE;
        float w1 = (float)(ec1 & 32767u) * W_SCALE;
        a0.x = fmaf(w0, bfu(r0.x), a0.x);
        a0.y = fmaf(w0, bfu(r0.y), a0.y);
        a0.z = fmaf(w0, bfu(r0.z), a0.z);
        a0.w = fmaf(w0, bfu(r0.w), a0.w);
        a1.x = fmaf(w1, bfu(r1.x), a1.x);
        a1.y = fmaf(w1, bfu(r1.y), a1.y);
        a1.z = fmaf(w1, bfu(r1.z), a1.z);
        a1.w = fmaf(w1, bfu(r1.w), a1.w);
        ec0 = en0; ec1 = en1; j += 8;
    }
    float4 acc;
    acc.x = a0.x + a1.x; acc.y = a0.y + a1.y; acc.z = a0.z + a1.z; acc.w = a0.w + a1.w;
    acc.x += __shfl_xor(acc.x, 16); acc.y += __shfl_xor(acc.y, 16);
    acc.z += __shfl_xor(acc.z, 16); acc.w += __shfl_xor(acc.w, 16);
    acc.x += __shfl_xor(acc.x, 32); acc.y += __shfl_xor(acc.y, 32);
    acc.z += __shfl_xor(acc.z, 32); acc.w += __shfl_xor(acc.w, 32);
    if (l < 16) {
        ushort4 st;
        st.x = f2bf(acc.x); st.y = f2bf(acc.y); st.z = f2bf(acc.z); st.w = f2bf(acc.w);
        ((ushort4*)(agg + node * 64))[q] = st;
    }
}

// ---------------------------------------------------------------------------
// MFMA transform 2: h2 = relu(agg2 @ Wrel2^T + b2 + h1 @ Wroot2^T), h1
// recomputed from pair p in bf16. D: col=lane&15=node, row=(lane>>4)*4+j=c.
__global__ __launch_bounds__(256) void k_transform2_mfma(
    const unsigned short* __restrict__ agg, const float2* __restrict__ p,
    const float* __restrict__ Wrel, const float* __restrict__ brel,
    const float* __restrict__ Wroot,
    const float* __restrict__ Wr1, const float* __restrict__ b1,
    const float* __restrict__ Wo1,
    unsigned short* __restrict__ h2)
{
    int t = threadIdx.x;
    int wv = t >> 6, l = t & 63;
    int lo = l & 15, hi = l >> 4;
    bf16x8 wR[4][2], wO[4][2];
    #pragma unroll
    for (int ct = 0; ct < 4; ++ct)
        #pragma unroll
        for (int kh = 0; kh < 2; ++kh) {
            wR[ct][kh] = load_wfrag(Wrel,  ct * 16 + lo, kh * 32 + hi * 8);
            wO[ct][kh] = load_wfrag(Wroot, ct * 16 + lo, kh * 32 + hi * 8);
        }
    float bias[4][4];
    #pragma unroll
    for (int ct = 0; ct < 4; ++ct)
        #pragma unroll
        for (int j = 0; j < 4; ++j) bias[ct][j] = brel[ct * 16 + hi * 4 + j];
    float w1a[16], w1b[16], w1c[16];           // [kh*8+j] at k = kh*32+hi*8+j
    #pragma unroll
    for (int kh = 0; kh < 2; ++kh)
        #pragma unroll
        for (int j = 0; j < 8; ++j) {
            int idx = kh * 32 + hi * 8 + j;
            w1a[kh * 8 + j] = Wr1[idx]; w1b[kh * 8 + j] = Wo1[idx]; w1c[kh * 8 + j] = b1[idx];
        }
    int wid = blockIdx.x * 4 + wv, nw = gridDim.x * 4;
    for (int tile = wid; tile < N_TILES; tile += nw) {
        int i = tile * 16 + lo;
        float2 pv = p[i];
        bf16x8 bA0 = *(const bf16x8*)(agg + i * 64 + hi * 8);
        bf16x8 bA1 = *(const bf16x8*)(agg + i * 64 + 32 + hi * 8);
        bf16x8 bH0, bH1;
        #pragma unroll
        for (int j = 0; j < 8; ++j) {
            float h0 = fmaxf(fmaf(pv.x, w1a[j],     fmaf(pv.y, w1b[j],     w1c[j])),     0.0f);
            float h1 = fmaxf(fmaf(pv.x, w1a[8 + j], fmaf(pv.y, w1b[8 + j], w1c[8 + j])), 0.0f);
            bH0[j] = (short)f2bf(h0);
            bH1[j] = (short)f2bf(h1);
        }
        #pragma unroll
        for (int ct = 0; ct < 4; ++ct) {
            f32x4 acc = {bias[ct][0], bias[ct][1], bias[ct][2], bias[ct][3]};
            acc = __builtin_amdgcn_mfma_f32_16x16x32_bf16(wR[ct][0], bA0, acc, 0, 0, 0);
            acc = __builtin_amdgcn_mfma_f32_16x16x32_bf16(wR[ct][1], bA1, acc, 0, 0, 0);
            acc = __builtin_amdgcn_mfma_f32_16x16x32_bf16(wO[ct][0], bH0, acc, 0, 0, 0);
            acc = __builtin_amdgcn_mfma_f32_16x16x32_bf16(wO[ct][1], bH1, acc, 0, 0, 0);
            ushort4 st;
            st.x = f2bf(fmaxf(acc[0], 0.0f)); st.y = f2bf(fmaxf(acc[1], 0.0f));
            st.z = f2bf(fmaxf(acc[2], 0.0f)); st.w = f2bf(fmaxf(acc[3], 0.0f));
            *(ushort4*)(h2 + i * 64 + ct * 16 + hi * 4) = st;
        }
    }
}

// Butterfly-reduce pool over the 16 node-lanes; lanes lo==0 flush to sums.
__device__ __forceinline__ void flush_pool(float* pool, int gcur, float* __restrict__ sums,
                                           int lo, int hi) {
    #pragma unroll
    for (int n = 0; n < 16; ++n) {
        float v = pool[n];
        v += __shfl_xor(v, 1); v += __shfl_xor(v, 2);
        v += __shfl_xor(v, 4); v += __shfl_xor(v, 8);
        if (lo == 0) atomicAdd(&sums[gcur * 64 + (n >> 2) * 16 + hi * 4 + (n & 3)], v);
        pool[n] = 0.0f;
    }
}

// MFMA transform 3 + fused mean-pool stage 1 (no relu; h3 never hits memory).
__global__ __launch_bounds__(256) void k_transform3_pool_mfma(
    const unsigned short* __restrict__ agg, const unsigned short* __restrict__ h2,
    const float* __restrict__ Wrel, const float* __restrict__ brel,
    const float* __restrict__ Wroot, const int* __restrict__ batch,
    float* __restrict__ sums)
{
    int t = threadIdx.x;
    int wv = t >> 6, l = t & 63;
    int lo = l & 15, hi = l >> 4;
    bf16x8 wR[4][2], wO[4][2];
    #pragma unroll
    for (int ct = 0; ct < 4; ++ct)
        #pragma unroll
        for (int kh = 0; kh < 2; ++kh) {
            wR[ct][kh] = load_wfrag(Wrel,  ct * 16 + lo, kh * 32 + hi * 8);
            wO[ct][kh] = load_wfrag(Wroot, ct * 16 + lo, kh * 32 + hi * 8);
        }
    float bias[4][4];
    #pragma unroll
    for (int ct = 0; ct < 4; ++ct)
        #pragma unroll
        for (int j = 0; j < 4; ++j) bias[ct][j] = brel[ct * 16 + hi * 4 + j];

    int nw = gridDim.x * 4;
    int wid = blockIdx.x * 4 + wv;
    int tpw = (N_TILES + nw - 1) / nw;
    int t0 = wid * tpw, t1 = min(t0 + tpw, N_TILES);
    if (t0 >= t1) return;

    float pool[16];
    #pragma unroll
    for (int n = 0; n < 16; ++n) pool[n] = 0.0f;
    int gcur = batch[t0 * 16];

    for (int tile = t0; tile < t1; ++tile) {
        int i = tile * 16 + lo;
        int gi = batch[i];
        bf16x8 bA0 = *(const bf16x8*)(agg + i * 64 + hi * 8);
        bf16x8 bA1 = *(const bf16x8*)(agg + i * 64 + 32 + hi * 8);
        bf16x8 bH0 = *(const bf16x8*)(h2  + i * 64 + hi * 8);
        bf16x8 bH1 = *(const bf16x8*)(h2  + i * 64 + 32 + hi * 8);
        f32x4 acc[4];
        #pragma unroll
        for (int ct = 0; ct < 4; ++ct) {
            f32x4 a = {bias[ct][0], bias[ct][1], bias[ct][2], bias[ct][3]};
            a = __builtin_amdgcn_mfma_f32_16x16x32_bf16(wR[ct][0], bA0, a, 0, 0, 0);
            a = __builtin_amdgcn_mfma_f32_16x16x32_bf16(wR[ct][1], bA1, a, 0, 0, 0);
            a = __builtin_amdgcn_mfma_f32_16x16x32_bf16(wO[ct][0], bH0, a, 0, 0, 0);
            a = __builtin_amdgcn_mfma_f32_16x16x32_bf16(wO[ct][1], bH1, a, 0, 0, 0);
            acc[ct] = a;
        }
        int gfirst = __shfl(gi, 0);
        int glast  = __shfl(gi, 15);
        if (gfirst != glast) {
            flush_pool(pool, gcur, sums, lo, hi);
            #pragma unroll
            for (int ct = 0; ct < 4; ++ct)
                #pragma unroll
                for (int j = 0; j < 4; ++j)
                    atomicAdd(&sums[gi * 64 + ct * 16 + hi * 4 + j], acc[ct][j]);
            gcur = glast;
        } else {
            if (gfirst != gcur) {
                flush_pool(pool, gcur, sums, lo, hi);
                gcur = gfirst;
            }
            #pragma unroll
            for (int ct = 0; ct < 4; ++ct)
                #pragma unroll
                for (int j = 0; j < 4; ++j) pool[ct * 4 + j] += acc[ct][j];
        }
    }
    flush_pool(pool, gcur, sums, lo, hi);
}

// Pool stage 2: pooled = sums/count; out = pooled @ Wlin^T + blin. One wave/graph.
__global__ __launch_bounds__(64) void k_pool2(
    const float* __restrict__ sums, const int* __restrict__ batch,
    const float* __restrict__ Wlin, const float* __restrict__ blin,
    float* __restrict__ out)
{
    int g = blockIdx.x;
    int c = threadIdx.x;
    int lo = 0, hi = N_NODES;
    while (lo < hi) { int mid = (lo + hi) >> 1; if (batch[mid] < g) lo = mid + 1; else hi = mid; }
    int s0 = lo;
    lo = 0; hi = N_NODES;
    while (lo < hi) { int mid = (lo + hi) >> 1; if (batch[mid] < g + 1) lo = mid + 1; else hi = mid; }
    int s1 = lo;
    __shared__ float pooled[64];
    float cnt = (float)(s1 - s0);
    pooled[c] = sums[g * 64 + c] / fmaxf(cnt, 1.0f);
    __syncthreads();
    if (c < OUT_CH) {
        float acc = blin[c];
        #pragma unroll 8
        for (int k = 0; k < HIDDEN; ++k) acc += pooled[k] * Wlin[c * 64 + k];
        out[g * OUT_CH + c] = acc;
    }
}

// ---------------------------------------------------------------------------
extern "C" void kernel_launch(void* const* d_in, const int* in_sizes, int n_in,
                              void* d_out, int out_size, void* d_ws, size_t ws_size,
                              hipStream_t stream)
{
    const float* x    = (const float*)d_in[0];
    const int*   ei   = (const int*)d_in[1];      // [2, E]: row0=src, row1=dst
    const int*   src  = ei;
    const int*   dst  = ei + N_EDGES;
    const float* ew   = (const float*)d_in[2];
    const int*   batch= (const int*)d_in[3];
    const float* Wr1  = (const float*)d_in[4];
    const float* b1   = (const float*)d_in[5];
    const float* Wo1  = (const float*)d_in[6];
    const float* Wr2  = (const float*)d_in[7];
    const float* b2   = (const float*)d_in[8];
    const float* Wo2  = (const float*)d_in[9];
    const float* Wr3  = (const float*)d_in[10];
    const float* b3   = (const float*)d_in[11];
    const float* Wo3  = (const float*)d_in[12];
    const float* Wlin = (const float*)d_in[13];
    const float* blin = (const float*)d_in[14];
    float* out = (float*)d_out;

    // workspace layout (~50 MB; 78.6 MB proven safe in round 0)
    char* ws = (char*)d_ws;
    const size_t K = 1024;
    int*            row_ptr = (int*)(ws + 0);               // 404 KB (NN2+1 ints)
    int*            bmat    = (int*)(ws + 512 * K);         // 391*256*4 = 400 KB
    int*            btotal  = (int*)(ws + 1024 * K);        // 1.6 KB
    int*            cbase   = (int*)(ws + 1028 * K);        // 1.6 KB
    int*            bsum    = (int*)(ws + 1032 * K);
    int*            boff    = (int*)(ws + 1036 * K);
    int*            pcnt    = (int*)(ws + 1040 * K);        // 400 KB
    float*          sums    = (float*)(ws + 1444 * K);      // 16 KB pool partials
    float2*         p       = (float2*)(ws + 1536 * K);     // 800 KB
    uint2*          C       = (uint2*)(ws + 2560 * K);      // 12.8 MB
    unsigned*       E       = (unsigned*)(ws + 15360 * K);  // up to 7.6 MB (padded CSR)
    unsigned short* h2      = (unsigned short*)(ws + 23552 * K); // 12.8 MB
    unsigned short* aggbuf  = (unsigned short*)(ws + 36864 * K); // 12.8 MB (bf16)

    // ---- CSR build: 3-phase counting sort (no global position atomics) ----
    hipMemsetAsync(E, 0, 7800 * K, stream);                       // padding zeros
    hipMemsetAsync(sums, 0, N_GRAPHS * HIDDEN * sizeof(float), stream);
    k_bhist<<<CBLK, 256, 0, stream>>>(dst, bmat);
    k_colscan<<<NBUCK, 256, 0, stream>>>(bmat, btotal);
    k_scan_bsum<<<1, 512, 0, stream>>>(btotal, cbase);
    k_coarse<<<CBLK, 256, 0, stream>>>(src, dst, ew, bmat, cbase, C);
    k_fhist<<<NBUCK, 256, 0, stream>>>(C, cbase, btotal, pcnt);
    k_partial<<<NB1, SCAN_B, 0, stream>>>(pcnt, bsum);
    k_scan_bsum<<<1, 512, 0, stream>>>(bsum, boff);
    k_scan_final<<<NB1, SCAN_B, 0, stream>>>(pcnt, boff, row_ptr);
    k_fine<<<NBUCK, 256, 0, stream>>>(C, cbase, btotal, row_ptr, x, E, p);  // + fused layer-1 agg

    // ---- layer 2: gather from pairs (bf16 agg), MFMA transform -> h2 (bf16) ----
    k_gather_pair<<<(N_NODES * 64) / 256, 256, 0, stream>>>(row_ptr, E, p, Wr1, b1, Wo1, aggbuf);
    k_transform2_mfma<<<512, 256, 0, stream>>>(aggbuf, p, Wr2, b2, Wo2, Wr1, b1, Wo1, h2);

    // ---- layer 3: gather bf16 rows, MFMA transform fused with pool stage 1 ----
    k_gather_bf16<<<(N_NODES * 64) / 256, 256, 0, stream>>>(row_ptr, E, h2, aggbuf);
    k_transform3_pool_mfma<<<512, 256, 0, stream>>>(aggbuf, h2, Wr3, b3, Wo3, batch, sums);

    // ---- pool stage 2: divide + 64->16 linear ----
    k_pool2<<<N_GRAPHS, 64, 0, stream>>>(sums, batch, Wlin, blin, out);
}

// Round 12
// 287.390 us; speedup vs baseline: 11.3925x; 1.0290x over previous
//
#include <hip/hip_runtime.h>

#define N_NODES 100000
#define N_EDGES 1600000
#define HIDDEN 64
#define OUT_CH 16
#define N_GRAPHS 64
#define N_TILES 6250                  // N_NODES / 16
#define SCAN_B 256
#define NB1 391                       // scan blocks; also NBUCK (100096/256)
#define NBUCK 391                     // coarse buckets (dst >> 8)
#define NN2 (NBUCK * 256)             // 100096: padded node space
#define CBLK 250                      // coarse blocks
#define EPB 6400                      // edges per coarse block (250*6400 = 1.6M)
#define W_SCALE (1.0f / 32767.0f)

typedef __attribute__((ext_vector_type(8))) short bf16x8;
typedef __attribute__((ext_vector_type(4))) float f32x4;

__device__ __forceinline__ float bfu(unsigned short u) {            // bf16 -> f32
    return __uint_as_float(((unsigned)u) << 16);
}
__device__ __forceinline__ unsigned short f2bf(float x) {           // f32 -> bf16 RTN
    unsigned u = __float_as_uint(x);
    return (unsigned short)((u + 0x7FFFu + ((u >> 16) & 1u)) >> 16);
}
// load 8 consecutive f32 of W row c starting at k0, convert to bf16x8 frag
__device__ __forceinline__ bf16x8 load_wfrag(const float* __restrict__ W, int c, int k0) {
    float4 a = *(const float4*)(W + c * 64 + k0);
    float4 b = *(const float4*)(W + c * 64 + k0 + 4);
    bf16x8 r;
    r[0] = (short)f2bf(a.x); r[1] = (short)f2bf(a.y); r[2] = (short)f2bf(a.z); r[3] = (short)f2bf(a.w);
    r[4] = (short)f2bf(b.x); r[5] = (short)f2bf(b.y); r[6] = (short)f2bf(b.z); r[7] = (short)f2bf(b.w);
    return r;
}

// ---------------------------------------------------------------------------
// Phase A1: per-block coarse-bucket histogram (LDS) -> bmat[b][blk]
__global__ __launch_bounds__(256) void k_bhist(const int* __restrict__ dst, int* __restrict__ bmat) {
    __shared__ int bh[NBUCK];
    int t = threadIdx.x, blk = blockIdx.x;
    for (int b = t; b < NBUCK; b += 256) bh[b] = 0;
    __syncthreads();
    int base = blk * EPB;
    for (int r = 0; r < EPB / 256; ++r)
        atomicAdd(&bh[dst[base + r * 256 + t] >> 8], 1);
    __syncthreads();
    for (int b = t; b < NBUCK; b += 256) bmat[b * 256 + blk] = bh[b];
}

// Phase A2: per-bucket exclusive scan over the 250 block counts (column scan)
__global__ __launch_bounds__(256) void k_colscan(int* __restrict__ bmat, int* __restrict__ btotal) {
    __shared__ int s[256];
    int b = blockIdx.x, t = threadIdx.x;
    int v = (t < CBLK) ? bmat[b * 256 + t] : 0;
    s[t] = v;
    __syncthreads();
    for (int off = 1; off < 256; off <<= 1) {
        int x = (t >= off) ? s[t - off] : 0;
        __syncthreads();
        s[t] += x;
        __syncthreads();
    }
    if (t < CBLK) bmat[b * 256 + t] = s[t] - v;   // exclusive within column
    if (t == 255) btotal[b] = s[255];
}

// Generic 391-length exclusive scan in one block (used for cbase and boff)
__global__ __launch_bounds__(512) void k_scan_bsum(const int* __restrict__ in, int* __restrict__ outp) {
    __shared__ int s[512];
    int t = threadIdx.x;
    int v = (t < NB1) ? in[t] : 0;
    s[t] = v;
    __syncthreads();
    for (int off = 1; off < 512; off <<= 1) {
        int x = (t >= off) ? s[t - off] : 0;
        __syncthreads();
        s[t] += x;
        __syncthreads();
    }
    if (t < NB1) outp[t] = s[t] - v;   // exclusive
}

// Phase A3: coarse scatter. Each (block,bucket) owns an exclusive contiguous
// run in C -> writes are short contiguous runs (L2 merges within one XCD).
__global__ __launch_bounds__(256) void k_coarse(
    const int* __restrict__ src, const int* __restrict__ dst, const float* __restrict__ w,
    const int* __restrict__ bmat, const int* __restrict__ cbase, uint2* __restrict__ C)
{
    __shared__ int cur[NBUCK];
    int t = threadIdx.x, blk = blockIdx.x;
    for (int b = t; b < NBUCK; b += 256) cur[b] = cbase[b] + bmat[b * 256 + blk];
    __syncthreads();
    int base = blk * EPB;
    for (int r = 0; r < EPB / 256; ++r) {
        int e = base + r * 256 + t;
        int d = dst[e];
        int q = __float2int_rn(w[e] * 32767.0f);
        unsigned pe = ((unsigned)src[e] << 15) | (unsigned)q;
        int pos = atomicAdd(&cur[d >> 8], 1);
        C[pos] = make_uint2(pe, (unsigned)(d & 255));
    }
}

// Phase B1: per-node counts within each bucket (coalesced region read)
__global__ __launch_bounds__(256) void k_fhist(const uint2* __restrict__ C, const int* __restrict__ cbase,
                                               const int* __restrict__ btotal, int* __restrict__ pcnt) {
    __shared__ int c[256];
    int b = blockIdx.x, t = threadIdx.x;
    c[t] = 0;
    __syncthreads();
    int j0 = cbase[b], j1 = j0 + btotal[b];
    for (int j = j0 + t; j < j1; j += 256) atomicAdd(&c[C[j].y], 1);
    __syncthreads();
    pcnt[b * 256 + t] = c[t];
}

// Phase B2a: per-block sums of PADDED counts (rows padded to multiple of 4)
__global__ __launch_bounds__(SCAN_B) void k_partial(const int* __restrict__ pcnt, int* __restrict__ bsum) {
    __shared__ int s[SCAN_B];
    int b = blockIdx.x, t = threadIdx.x;
    s[t] = (pcnt[b * SCAN_B + t] + 3) & ~3;
    __syncthreads();
    for (int off = SCAN_B / 2; off > 0; off >>= 1) {
        if (t < off) s[t] += s[t + off];
        __syncthreads();
    }
    if (t == 0) bsum[b] = s[0];
}

// Phase B2b: per-block exclusive scan of padded counts -> row_ptr
__global__ __launch_bounds__(SCAN_B) void k_scan_final(const int* __restrict__ pcnt, const int* __restrict__ boff,
                                                       int* __restrict__ row_ptr) {
    __shared__ int s[SCAN_B];
    int b = blockIdx.x, t = threadIdx.x;
    int i = b * SCAN_B + t;
    int v = (pcnt[i] + 3) & ~3;
    s[t] = v;
    __syncthreads();
    for (int off = 1; off < SCAN_B; off <<= 1) {
        int x = (t >= off) ? s[t - off] : 0;
        __syncthreads();
        s[t] += x;
        __syncthreads();
    }
    row_ptr[i] = boff[b] + s[t] - v;
    if (i == NN2 - 1) row_ptr[NN2] = boff[b] + s[t];   // padded total
}

// Phase B3: fine scatter + zero-padding + FUSED layer-1 aggregation.
// One block per bucket -> single writer -> lines merge. Each thread then
// zeroes its node's <=3 pad slots (replaces the 8MB E memset) and
// aggregates its node's row (L2-hot E) into p = (agg1, x), 2-wide pipelined.
__global__ __launch_bounds__(256) void k_fine(const uint2* __restrict__ C, const int* __restrict__ cbase,
                                              const int* __restrict__ btotal, const int* __restrict__ row_ptr,
                                              const float* __restrict__ x,
                                              unsigned* __restrict__ E, float2* __restrict__ p) {
    __shared__ int cur[256];
    int b = blockIdx.x, t = threadIdx.x;
    int i = b * 256 + t;
    int rp0 = row_ptr[i];
    int rp1 = row_ptr[i + 1];
    cur[t] = rp0;
    __syncthreads();
    int j0 = cbase[b], j1 = j0 + btotal[b];
    for (int j = j0 + t; j < j1; j += 256) {
        uint2 c = C[j];
        int pos = atomicAdd(&cur[c.y], 1);
        E[pos] = c.x;
    }
    __syncthreads();
    int jend = cur[t];
    for (int j = jend; j < rp1; ++j) E[j] = 0u;     // zero pad slots
    if (i < N_NODES) {
        float acc0 = 0.0f, acc1 = 0.0f;
        int j = rp0;
        unsigned e0 = (j     < jend) ? E[j]     : 0u;
        unsigned e1 = (j + 1 < jend) ? E[j + 1] : 0u;
        while (j < jend) {
            float x0 = x[e0 >> 15];
            float x1 = x[e1 >> 15];
            unsigned n0 = (j + 2 < jend) ? E[j + 2] : 0u;
            unsigned n1 = (j + 3 < jend) ? E[j + 3] : 0u;
            acc0 = fmaf((float)(e0 & 32767u) * W_SCALE, x0, acc0);
            acc1 = fmaf((float)(e1 & 32767u) * W_SCALE, x1, acc1);
            e0 = n0; e1 = n1; j += 2;
        }
        p[i] = make_float2(acc0 + acc1, x[i]);
    }
}

// ---------------------------------------------------------------------------
// Layer-2 aggregation, grouped + 4-deep pipelined: 4 lane-groups of 16; group
// g owns edge slot j+g; lane handles channels 4q..4q+3. Up to 8 loads in
// flight (4 p + 4 E), 4 accumulator chains. Butterfly + bf16 ushort4 store.
__global__ __launch_bounds__(256) void k_gather_pair(
    const int* __restrict__ rp, const unsigned* __restrict__ E,
    const float2* __restrict__ p,
    const float* __restrict__ Wr1, const float* __restrict__ b1,
    const float* __restrict__ Wo1, unsigned short* __restrict__ agg)
{
    int t = blockIdx.x * 256 + threadIdx.x;
    int node = t >> 6;
    int l = t & 63;
    int g = l >> 4, q = l & 15;
    if (node >= N_NODES) return;
    float4 wr = *(const float4*)(Wr1 + q * 4);
    float4 wo = *(const float4*)(Wo1 + q * 4);
    float4 bb = *(const float4*)(b1  + q * 4);
    int j0 = rp[node], j1 = rp[node + 1];
    float4 a0 = make_float4(0.f, 0.f, 0.f, 0.f);
    float4 a1 = make_float4(0.f, 0.f, 0.f, 0.f);
    float4 a2 = make_float4(0.f, 0.f, 0.f, 0.f);
    float4 a3 = make_float4(0.f, 0.f, 0.f, 0.f);
    int j = j0;
    // zero entries (src=0, w=0) make all OOB prefetches harmless
    unsigned ec0 = (j      < j1) ? E[j + g]      : 0u;
    unsigned ec1 = (j + 4  < j1) ? E[j + 4 + g]  : 0u;
    unsigned ec2 = (j + 8  < j1) ? E[j + 8 + g]  : 0u;
    unsigned ec3 = (j + 12 < j1) ? E[j + 12 + g] : 0u;
    while (j < j1) {
        float2 p0 = p[ec0 >> 15];
        float2 p1 = p[ec1 >> 15];
        float2 p2 = p[ec2 >> 15];
        float2 p3 = p[ec3 >> 15];
        unsigned en0 = (j + 16 < j1) ? E[j + 16 + g] : 0u;
        unsigned en1 = (j + 20 < j1) ? E[j + 20 + g] : 0u;
        unsigned en2 = (j + 24 < j1) ? E[j + 24 + g] : 0u;
        unsigned en3 = (j + 28 < j1) ? E[j + 28 + g] : 0u;
        float w0 = (float)(ec0 & 32767u) * W_SCALE;
        float w1 = (float)(ec1 & 32767u) * W_SCALE;
        float w2 = (float)(ec2 & 32767u) * W_SCALE;
        float w3 = (float)(ec3 & 32767u) * W_SCALE;
        a0.x = fmaf(w0, fmaxf(fmaf(p0.x, wr.x, fmaf(p0.y, wo.x, bb.x)), 0.0f), a0.x);
        a0.y = fmaf(w0, fmaxf(fmaf(p0.x, wr.y, fmaf(p0.y, wo.y, bb.y)), 0.0f), a0.y);
        a0.z = fmaf(w0, fmaxf(fmaf(p0.x, wr.z, fmaf(p0.y, wo.z, bb.z)), 0.0f), a0.z);
        a0.w = fmaf(w0, fmaxf(fmaf(p0.x, wr.w, fmaf(p0.y, wo.w, bb.w)), 0.0f), a0.w);
        a1.x = fmaf(w1, fmaxf(fmaf(p1.x, wr.x, fmaf(p1.y, wo.x, bb.x)), 0.0f), a1.x);
        a1.y = fmaf(w1, fmaxf(fmaf(p1.x, wr.y, fmaf(p1.y, wo.y, bb.y)), 0.0f), a1.y);
        a1.z = fmaf(w1, fmaxf(fmaf(p1.x, wr.z, fmaf(p1.y, wo.z, bb.z)), 0.0f), a1.z);
        a1.w = fmaf(w1, fmaxf(fmaf(p1.x, wr.w, fmaf(p1.y, wo.w, bb.w)), 0.0f), a1.w);
        a2.x = fmaf(w2, fmaxf(fmaf(p2.x, wr.x, fmaf(p2.y, wo.x, bb.x)), 0.0f), a2.x);
        a2.y = fmaf(w2, fmaxf(fmaf(p2.x, wr.y, fmaf(p2.y, wo.y, bb.y)), 0.0f), a2.y);
        a2.z = fmaf(w2, fmaxf(fmaf(p2.x, wr.z, fmaf(p2.y, wo.z, bb.z)), 0.0f), a2.z);
        a2.w = fmaf(w2, fmaxf(fmaf(p2.x, wr.w, fmaf(p2.y, wo.w, bb.w)), 0.0f), a2.w);
        a3.x = fmaf(w3, fmaxf(fmaf(p3.x, wr.x, fmaf(p3.y, wo.x, bb.x)), 0.0f), a3.x);
        a3.y = fmaf(w3, fmaxf(fmaf(p3.x, wr.y, fmaf(p3.y, wo.y, bb.y)), 0.0f), a3.y);
        a3.z = fmaf(w3, fmaxf(fmaf(p3.x, wr.z, fmaf(p3.y, wo.z, bb.z)), 0.0f), a3.z);
        a3.w = fmaf(w3, fmaxf(fmaf(p3.x, wr.w, fmaf(p3.y, wo.w, bb.w)), 0.0f), a3.w);
        ec0 = en0; ec1 = en1; ec2 = en2; ec3 = en3; j += 16;
    }
    float4 acc;
    acc.x = (a0.x + a1.x) + (a2.x + a3.x);
    acc.y = (a0.y + a1.y) + (a2.y + a3.y);
    acc.z = (a0.z + a1.z) + (a2.z + a3.z);
    acc.w = (a0.w + a1.w) + (a2.w + a3.w);
    acc.x += __shfl_xor(acc.x, 16); acc.y += __shfl_xor(acc.y, 16);
    acc.z += __shfl_xor(acc.z, 16); acc.w += __shfl_xor(acc.w, 16);
    acc.x += __shfl_xor(acc.x, 32); acc.y += __shfl_xor(acc.y, 32);
    acc.z += __shfl_xor(acc.z, 32); acc.w += __shfl_xor(acc.w, 32);
    if (l < 16) {
        ushort4 st;
        st.x = f2bf(acc.x); st.y = f2bf(acc.y); st.z = f2bf(acc.z); st.w = f2bf(acc.w);
        ((ushort4*)(agg + node * 64))[q] = st;
    }
}

// ---------------------------------------------------------------------------
// Layer-3 aggregation, grouped + 4-deep pipelined: group g owns edge slot j+g;
// lane q loads 8B of the 128B row (coalesced per group). Up to 8 loads in
// flight, 4 accumulator chains. Butterfly reduce + bf16 ushort4 store.
__global__ __launch_bounds__(256) void k_gather_bf16(
    const int* __restrict__ rp, const unsigned* __restrict__ E,
    const unsigned short* __restrict__ h2, unsigned short* __restrict__ agg)
{
    int t = blockIdx.x * 256 + threadIdx.x;
    int node = t >> 6;
    int l = t & 63;
    int g = l >> 4, q = l & 15;
    if (node >= N_NODES) return;
    int j0 = rp[node], j1 = rp[node + 1];
    float4 a0 = make_float4(0.f, 0.f, 0.f, 0.f);
    float4 a1 = make_float4(0.f, 0.f, 0.f, 0.f);
    float4 a2 = make_float4(0.f, 0.f, 0.f, 0.f);
    float4 a3 = make_float4(0.f, 0.f, 0.f, 0.f);
    int j = j0;
    unsigned ec0 = (j      < j1) ? E[j + g]      : 0u;
    unsigned ec1 = (j + 4  < j1) ? E[j + 4 + g]  : 0u;
    unsigned ec2 = (j + 8  < j1) ? E[j + 8 + g]  : 0u;
    unsigned ec3 = (j + 12 < j1) ? E[j + 12 + g] : 0u;
    while (j < j1) {
        ushort4 r0 = *((const ushort4*)(h2 + (ec0 >> 15) * 64) + q);
        ushort4 r1 = *((const ushort4*)(h2 + (ec1 >> 15) * 64) + q);
        ushort4 r2 = *((const ushort4*)(h2 + (ec2 >> 15) * 64) + q);
        ushort4 r3 = *((const ushort4*)(h2 + (ec3 >> 15) * 64) + q);
        unsigned en0 = (j + 16 < j1) ? E[j + 16 + g] : 0u;
        unsigned en1 = (j + 20 < j1) ? E[j + 20 + g] : 0u;
        unsigned en2 = (j + 24 < j1) ? E[j + 24 + g] : 0u;
        unsigned en3 = (j + 28 < j1) ? E[j + 28 + g] : 0u;
        float w0 = (float)(ec0 & 32767u) * W_SCALE;
        float w1 = (float)(ec1 & 32767u) * W_SCALE;
        float w2 = (float)(ec2 & 32767u) * W_SCALE;
        float w3 = (float)(ec3 & 32767u) * W_SCALE;
        a0.x = fmaf(w0, bfu(r0.x), a0.x);
        a0.y = fmaf(w0, bfu(r0.y), a0.y);
        a0.z = fmaf(w0, bfu(r0.z), a0.z);
        a0.w = fmaf(w0, bfu(r0.w), a0.w);
        a1.x = fmaf(w1, bfu(r1.x), a1.x);
        a1.y = fmaf(w1, bfu(r1.y), a1.y);
        a1.z = fmaf(w1, bfu(r1.z), a1.z);
        a1.w = fmaf(w1, bfu(r1.w), a1.w);
        a2.x = fmaf(w2, bfu(r2.x), a2.x);
        a2.y = fmaf(w2, bfu(r2.y), a2.y);
        a2.z = fmaf(w2, bfu(r2.z), a2.z);
        a2.w = fmaf(w2, bfu(r2.w), a2.w);
        a3.x = fmaf(w3, bfu(r3.x), a3.x);
        a3.y = fmaf(w3, bfu(r3.y), a3.y);
        a3.z = fmaf(w3, bfu(r3.z), a3.z);
        a3.w = fmaf(w3, bfu(r3.w), a3.w);
        ec0 = en0; ec1 = en1; ec2 = en2; ec3 = en3; j += 16;
    }
    float4 acc;
    acc.x = (a0.x + a1.x) + (a2.x + a3.x);
    acc.y = (a0.y + a1.y) + (a2.y + a3.y);
    acc.z = (a0.z + a1.z) + (a2.z + a3.z);
    acc.w = (a0.w + a1.w) + (a2.w + a3.w);
    acc.x += __shfl_xor(acc.x, 16); acc.y += __shfl_xor(acc.y, 16);
    acc.z += __shfl_xor(acc.z, 16); acc.w += __shfl_xor(acc.w, 16);
    acc.x += __shfl_xor(acc.x, 32); acc.y += __shfl_xor(acc.y, 32);
    acc.z += __shfl_xor(acc.z, 32); acc.w += __shfl_xor(acc.w, 32);
    if (l < 16) {
        ushort4 st;
        st.x = f2bf(acc.x); st.y = f2bf(acc.y); st.z = f2bf(acc.z); st.w = f2bf(acc.w);
        ((ushort4*)(agg + node * 64))[q] = st;
    }
}

// ---------------------------------------------------------------------------
// MFMA transform 2: h2 = relu(agg2 @ Wrel2^T + b2 + h1 @ Wroot2^T), h1
// recomputed from pair p in bf16. D: col=lane&15=node, row=(lane>>4)*4+j=c.
__global__ __launch_bounds__(256) void k_transform2_mfma(
    const unsigned short* __restrict__ agg, const float2* __restrict__ p,
    const float* __restrict__ Wrel, const float* __restrict__ brel,
    const float* __restrict__ Wroot,
    const float* __restrict__ Wr1, const float* __restrict__ b1,
    const float* __restrict__ Wo1,
    unsigned short* __restrict__ h2)
{
    int t = threadIdx.x;
    int wv = t >> 6, l = t & 63;
    int lo = l & 15, hi = l >> 4;
    bf16x8 wR[4][2], wO[4][2];
    #pragma unroll
    for (int ct = 0; ct < 4; ++ct)
        #pragma unroll
        for (int kh = 0; kh < 2; ++kh) {
            wR[ct][kh] = load_wfrag(Wrel,  ct * 16 + lo, kh * 32 + hi * 8);
            wO[ct][kh] = load_wfrag(Wroot, ct * 16 + lo, kh * 32 + hi * 8);
        }
    float bias[4][4];
    #pragma unroll
    for (int ct = 0; ct < 4; ++ct)
        #pragma unroll
        for (int j = 0; j < 4; ++j) bias[ct][j] = brel[ct * 16 + hi * 4 + j];
    float w1a[16], w1b[16], w1c[16];           // [kh*8+j] at k = kh*32+hi*8+j
    #pragma unroll
    for (int kh = 0; kh < 2; ++kh)
        #pragma unroll
        for (int j = 0; j < 8; ++j) {
            int idx = kh * 32 + hi * 8 + j;
            w1a[kh * 8 + j] = Wr1[idx]; w1b[kh * 8 + j] = Wo1[idx]; w1c[kh * 8 + j] = b1[idx];
        }
    int wid = blockIdx.x * 4 + wv, nw = gridDim.x * 4;
    for (int tile = wid; tile < N_TILES; tile += nw) {
        int i = tile * 16 + lo;
        float2 pv = p[i];
        bf16x8 bA0 = *(const bf16x8*)(agg + i * 64 + hi * 8);
        bf16x8 bA1 = *(const bf16x8*)(agg + i * 64 + 32 + hi * 8);
        bf16x8 bH0, bH1;
        #pragma unroll
        for (int j = 0; j < 8; ++j) {
            float h0 = fmaxf(fmaf(pv.x, w1a[j],     fmaf(pv.y, w1b[j],     w1c[j])),     0.0f);
            float h1 = fmaxf(fmaf(pv.x, w1a[8 + j], fmaf(pv.y, w1b[8 + j], w1c[8 + j])), 0.0f);
            bH0[j] = (short)f2bf(h0);
            bH1[j] = (short)f2bf(h1);
        }
        #pragma unroll
        for (int ct = 0; ct < 4; ++ct) {
            f32x4 acc = {bias[ct][0], bias[ct][1], bias[ct][2], bias[ct][3]};
            acc = __builtin_amdgcn_mfma_f32_16x16x32_bf16(wR[ct][0], bA0, acc, 0, 0, 0);
            acc = __builtin_amdgcn_mfma_f32_16x16x32_bf16(wR[ct][1], bA1, acc, 0, 0, 0);
            acc = __builtin_amdgcn_mfma_f32_16x16x32_bf16(wO[ct][0], bH0, acc, 0, 0, 0);
            acc = __builtin_amdgcn_mfma_f32_16x16x32_bf16(wO[ct][1], bH1, acc, 0, 0, 0);
            ushort4 st;
            st.x = f2bf(fmaxf(acc[0], 0.0f)); st.y = f2bf(fmaxf(acc[1], 0.0f));
            st.z = f2bf(fmaxf(acc[2], 0.0f)); st.w = f2bf(fmaxf(acc[3], 0.0f));
            *(ushort4*)(h2 + i * 64 + ct * 16 + hi * 4) = st;
        }
    }
}

// Butterfly-reduce pool over the 16 node-lanes; lanes lo==0 flush to sums.
__device__ __forceinline__ void flush_pool(float* pool, int gcur, float* __restrict__ sums,
                                           int lo, int hi) {
    #pragma unroll
    for (int n = 0; n < 16; ++n) {
        float v = pool[n];
        v += __shfl_xor(v, 1); v += __shfl_xor(v, 2);
        v += __shfl_xor(v, 4); v += __shfl_xor(v, 8);
        if (lo == 0) atomicAdd(&sums[gcur * 64 + (n >> 2) * 16 + hi * 4 + (n & 3)], v);
        pool[n] = 0.0f;
    }
}

// MFMA transform 3 + fused mean-pool stage 1 (no relu; h3 never hits memory).
__global__ __launch_bounds__(256) void k_transform3_pool_mfma(
    const unsigned short* __restrict__ agg, const unsigned short* __restrict__ h2,
    const float* __restrict__ Wrel, const float* __restrict__ brel,
    const float* __restrict__ Wroot, const int* __restrict__ batch,
    float* __restrict__ sums)
{
    int t = threadIdx.x;
    int wv = t >> 6, l = t & 63;
    int lo = l & 15, hi = l >> 4;
    bf16x8 wR[4][2], wO[4][2];
    #pragma unroll
    for (int ct = 0; ct < 4; ++ct)
        #pragma unroll
        for (int kh = 0; kh < 2; ++kh) {
            wR[ct][kh] = load_wfrag(Wrel,  ct * 16 + lo, kh * 32 + hi * 8);
            wO[ct][kh] = load_wfrag(Wroot, ct * 16 + lo, kh * 32 + hi * 8);
        }
    float bias[4][4];
    #pragma unroll
    for (int ct = 0; ct < 4; ++ct)
        #pragma unroll
        for (int j = 0; j < 4; ++j) bias[ct][j] = brel[ct * 16 + hi * 4 + j];

    int nw = gridDim.x * 4;
    int wid = blockIdx.x * 4 + wv;
    int tpw = (N_TILES + nw - 1) / nw;
    int t0 = wid * tpw, t1 = min(t0 + tpw, N_TILES);
    if (t0 >= t1) return;

    float pool[16];
    #pragma unroll
    for (int n = 0; n < 16; ++n) pool[n] = 0.0f;
    int gcur = batch[t0 * 16];

    for (int tile = t0; tile < t1; ++tile) {
        int i = tile * 16 + lo;
        int gi = batch[i];
        bf16x8 bA0 = *(const bf16x8*)(agg + i * 64 + hi * 8);
        bf16x8 bA1 = *(const bf16x8*)(agg + i * 64 + 32 + hi * 8);
        bf16x8 bH0 = *(const bf16x8*)(h2  + i * 64 + hi * 8);
        bf16x8 bH1 = *(const bf16x8*)(h2  + i * 64 + 32 + hi * 8);
        f32x4 acc[4];
        #pragma unroll
        for (int ct = 0; ct < 4; ++ct) {
            f32x4 a = {bias[ct][0], bias[ct][1], bias[ct][2], bias[ct][3]};
            a = __builtin_amdgcn_mfma_f32_16x16x32_bf16(wR[ct][0], bA0, a, 0, 0, 0);
            a = __builtin_amdgcn_mfma_f32_16x16x32_bf16(wR[ct][1], bA1, a, 0, 0, 0);
            a = __builtin_amdgcn_mfma_f32_16x16x32_bf16(wO[ct][0], bH0, a, 0, 0, 0);
            a = __builtin_amdgcn_mfma_f32_16x16x32_bf16(wO[ct][1], bH1, a, 0, 0, 0);
            acc[ct] = a;
        }
        int gfirst = __shfl(gi, 0);
        int glast  = __shfl(gi, 15);
        if (gfirst != glast) {
            flush_pool(pool, gcur, sums, lo, hi);
            #pragma unroll
            for (int ct = 0; ct < 4; ++ct)
                #pragma unroll
                for (int j = 0; j < 4; ++j)
                    atomicAdd(&sums[gi * 64 + ct * 16 + hi * 4 + j], acc[ct][j]);
            gcur = glast;
        } else {
            if (gfirst != gcur) {
                flush_pool(pool, gcur, sums, lo, hi);
                gcur = gfirst;
            }
            #pragma unroll
            for (int ct = 0; ct < 4; ++ct)
                #pragma unroll
                for (int j = 0; j < 4; ++j) pool[ct * 4 + j] += acc[ct][j];
        }
    }
    flush_pool(pool, gcur, sums, lo, hi);
}

// Pool stage 2: pooled = sums/count; out = pooled @ Wlin^T + blin. One wave/graph.
__global__ __launch_bounds__(64) void k_pool2(
    const float* __restrict__ sums, const int* __restrict__ batch,
    const float* __restrict__ Wlin, const float* __restrict__ blin,
    float* __restrict__ out)
{
    int g = blockIdx.x;
    int c = threadIdx.x;
    int lo = 0, hi = N_NODES;
    while (lo < hi) { int mid = (lo + hi) >> 1; if (batch[mid] < g) lo = mid + 1; else hi = mid; }
    int s0 = lo;
    lo = 0; hi = N_NODES;
    while (lo < hi) { int mid = (lo + hi) >> 1; if (batch[mid] < g + 1) lo = mid + 1; else hi = mid; }
    int s1 = lo;
    __shared__ float pooled[64];
    float cnt = (float)(s1 - s0);
    pooled[c] = sums[g * 64 + c] / fmaxf(cnt, 1.0f);
    __syncthreads();
    if (c < OUT_CH) {
        float acc = blin[c];
        #pragma unroll 8
        for (int k = 0; k < HIDDEN; ++k) acc += pooled[k] * Wlin[c * 64 + k];
        out[g * OUT_CH + c] = acc;
    }
}

// ---------------------------------------------------------------------------
extern "C" void kernel_launch(void* const* d_in, const int* in_sizes, int n_in,
                              void* d_out, int out_size, void* d_ws, size_t ws_size,
                              hipStream_t stream)
{
    const float* x    = (const float*)d_in[0];
    const int*   ei   = (const int*)d_in[1];      // [2, E]: row0=src, row1=dst
    const int*   src  = ei;
    const int*   dst  = ei + N_EDGES;
    const float* ew   = (const float*)d_in[2];
    const int*   batch= (const int*)d_in[3];
    const float* Wr1  = (const float*)d_in[4];
    const float* b1   = (const float*)d_in[5];
    const float* Wo1  = (const float*)d_in[6];
    const float* Wr2  = (const float*)d_in[7];
    const float* b2   = (const float*)d_in[8];
    const float* Wo2  = (const float*)d_in[9];
    const float* Wr3  = (const float*)d_in[10];
    const float* b3   = (const float*)d_in[11];
    const float* Wo3  = (const float*)d_in[12];
    const float* Wlin = (const float*)d_in[13];
    const float* blin = (const float*)d_in[14];
    float* out = (float*)d_out;

    // workspace layout (~50 MB; 78.6 MB proven safe in round 0)
    char* ws = (char*)d_ws;
    const size_t K = 1024;
    int*            row_ptr = (int*)(ws + 0);               // 404 KB (NN2+1 ints)
    int*            bmat    = (int*)(ws + 512 * K);         // 391*256*4 = 400 KB
    int*            btotal  = (int*)(ws + 1024 * K);        // 1.6 KB
    int*            cbase   = (int*)(ws + 1028 * K);        // 1.6 KB
    int*            bsum    = (int*)(ws + 1032 * K);
    int*            boff    = (int*)(ws + 1036 * K);
    int*            pcnt    = (int*)(ws + 1040 * K);        // 400 KB
    float*          sums    = (float*)(ws + 1444 * K);      // 16 KB pool partials
    float2*         p       = (float2*)(ws + 1536 * K);     // 800 KB
    uint2*          C       = (uint2*)(ws + 2560 * K);      // 12.8 MB
    unsigned*       E       = (unsigned*)(ws + 15360 * K);  // up to 7.6 MB (padded CSR)
    unsigned short* h2      = (unsigned short*)(ws + 23552 * K); // 12.8 MB
    unsigned short* aggbuf  = (unsigned short*)(ws + 36864 * K); // 12.8 MB (bf16)

    // ---- CSR build: 3-phase counting sort (no global position atomics) ----
    hipMemsetAsync(sums, 0, N_GRAPHS * HIDDEN * sizeof(float), stream);
    k_bhist<<<CBLK, 256, 0, stream>>>(dst, bmat);
    k_colscan<<<NBUCK, 256, 0, stream>>>(bmat, btotal);
    k_scan_bsum<<<1, 512, 0, stream>>>(btotal, cbase);
    k_coarse<<<CBLK, 256, 0, stream>>>(src, dst, ew, bmat, cbase, C);
    k_fhist<<<NBUCK, 256, 0, stream>>>(C, cbase, btotal, pcnt);
    k_partial<<<NB1, SCAN_B, 0, stream>>>(pcnt, bsum);
    k_scan_bsum<<<1, 512, 0, stream>>>(bsum, boff);
    k_scan_final<<<NB1, SCAN_B, 0, stream>>>(pcnt, boff, row_ptr);
    k_fine<<<NBUCK, 256, 0, stream>>>(C, cbase, btotal, row_ptr, x, E, p);  // + pad-zero + agg1

    // ---- layer 2: gather from pairs (bf16 agg), MFMA transform -> h2 (bf16) ----
    k_gather_pair<<<(N_NODES * 64) / 256, 256, 0, stream>>>(row_ptr, E, p, Wr1, b1, Wo1, aggbuf);
    k_transform2_mfma<<<512, 256, 0, stream>>>(aggbuf, p, Wr2, b2, Wo2, Wr1, b1, Wo1, h2);

    // ---- layer 3: gather bf16 rows, MFMA transform fused with pool stage 1 ----
    k_gather_bf16<<<(N_NODES * 64) / 256, 256, 0, stream>>>(row_ptr, E, h2, aggbuf);
    k_transform3_pool_mfma<<<512, 256, 0, stream>>>(aggbuf, h2, Wr3, b3, Wo3, batch, sums);

    // ---- pool stage 2: divide + 64->16 linear ----
    k_pool2<<<N_GRAPHS, 64, 0, stream>>>(sums, batch, Wlin, blin, out);
}